// Round 6
// baseline (709.423 us; speedup 1.0000x reference)
//
#include <hip/hip_runtime.h>

#define NB 32
#define NA 9
#define FH 100
#define FW 100
#define HWSZ (FH*FW)          // 10000
#define NANCH (HWSZ*NA)       // 90000
#define PRE 6000
#define POST 300
#define SORTN 8192
#define NWORD 188             // ceil(6000/32)
#define NEGV -1000000000.0f
#define NMS_T 0.7f
#define NT 256                // k_nms threads (4 waves, 1/SIMD)
#define KPT 24                // boxes per thread: 256*24 = 6144 >= 6000 (contiguous)
#define BIGI 0x7FFFFFFF
#define SWZ(i) ((i) ^ (((i) >> 3) & 7))   // LDS float4 bank-spread swizzle

__device__ __forceinline__ unsigned int f2sort(float f) {
  unsigned int u = __float_as_uint(f);
  return (u & 0x80000000u) ? ~u : (u | 0x80000000u);
}

// Decode one anchor's clipped box. i in [0, NANCH): i = (h*FW + w)*NA + a
__device__ __forceinline__ float4 decode_box(const float* __restrict__ pred,
                                             const float* __restrict__ anchors,
                                             int b, int i, float imw, float imh) {
  int hw = i / NA; int a = i - hw * NA;
  int h = hw / FW; int w = hw - h * FW;
  float sx = (float)(w * 16);
  float sy = (float)(h * 16);
  float ax1 = anchors[a*4+0] + sx, ay1 = anchors[a*4+1] + sy;
  float ax2 = anchors[a*4+2] + sx, ay2 = anchors[a*4+3] + sy;
  float wa = ax2 - ax1 + 1.0f, ha = ay2 - ay1 + 1.0f;
  float cxa = ax1 + 0.5f*(wa - 1.0f), cya = ay1 + 0.5f*(ha - 1.0f);
  size_t base = (((size_t)b*36 + a*4)*FH + h)*FW + w;
  float dx = pred[base];
  float dy = pred[base + HWSZ];
  float dw = pred[base + 2*HWSZ];
  float dh = pred[base + 3*HWSZ];
  float cx = dx*wa + cxa, cy = dy*ha + cya;
  float pw = expf(dw)*wa, ph = expf(dh)*ha;
  float x1 = fminf(fmaxf(cx - 0.5f*(pw - 1.0f), 0.0f), imw - 1.0f);
  float y1 = fminf(fmaxf(cy - 0.5f*(ph - 1.0f), 0.0f), imh - 1.0f);
  float x2 = fminf(fmaxf(cx + 0.5f*(pw - 1.0f), 0.0f), imw - 1.0f);
  float y2 = fminf(fmaxf(cy + 0.5f*(ph - 1.0f), 0.0f), imh - 1.0f);
  return make_float4(x1, y1, x2, y2);
}

// K1: per-anchor score with min-size filter -> sortable key
__global__ void k_decode(const float* __restrict__ cls,
                         const float* __restrict__ pred,
                         const float* __restrict__ iminfo,
                         const float* __restrict__ anchors,
                         unsigned long long* __restrict__ keys) {
  int gid = blockIdx.x * blockDim.x + threadIdx.x;
  if (gid >= NB * NANCH) return;
  int b = gid / NANCH;
  int i = gid - b * NANCH;
  int hw = i / NA; int a = i - hw * NA;
  int h = hw / FW; int w = hw - h * FW;
  float score = cls[(((size_t)b*18 + 9 + a)*FH + h)*FW + w];
  float imh = iminfo[b*3+0], imw = iminfo[b*3+1], sc = iminfo[b*3+2];
  float4 bx = decode_box(pred, anchors, b, i, imw, imh);
  float msz = 16.0f * sc;
  bool keep = ((bx.z - bx.x + 1.0f) >= msz) && ((bx.w - bx.y + 1.0f) >= msz);
  float sf = keep ? score : NEGV;
  unsigned long long key = ((unsigned long long)f2sort(sf) << 32)
                         | (unsigned int)(~(unsigned int)i);
  keys[(size_t)b * NANCH + i] = key;
}

// K2: per-batch block: radix-threshold select -> compact -> bitonic sort ->
// decode top-6000 boxes + live mask to GLOBAL
#define SMEM_BYTES (65536 + 16384 + 16384 + 64)
__global__ __launch_bounds__(1024, 1) void k_select(
    const unsigned long long* __restrict__ keys,
    const float* __restrict__ pred,
    const float* __restrict__ iminfo,
    const float* __restrict__ anchors,
    float4* __restrict__ boxes_g,
    unsigned int* __restrict__ live_g) {
  __shared__ __align__(16) unsigned char smemRaw[SMEM_BYTES];
  unsigned long long* cand = (unsigned long long*)smemRaw;            // [8192] 65536B
  unsigned int* histA = (unsigned int*)(smemRaw + 65536);             // [4096]
  unsigned int* histB = (unsigned int*)(smemRaw + 81920);             // [4096]
  int* scal = (int*)(smemRaw + 98304);                                // [16]

  const int b = blockIdx.x;
  const int tid = threadIdx.x;
  const int lane = tid & 63;
  const unsigned long long* kb = keys + (size_t)b * NANCH;

  // ---- level-1 histogram: sortable bits [31:20] ----
  for (int i = tid; i < 4096; i += 1024) histA[i] = 0;
  __syncthreads();
  for (int i = tid; i < NANCH; i += 1024)
    atomicAdd(&histA[(unsigned int)(kb[i] >> 52)], 1u);
  __syncthreads();
  {
    unsigned int *src = histA, *dst = histB;
    for (int d = 1; d < 4096; d <<= 1) {
      for (int i = tid; i < 4096; i += 1024) {
        unsigned int v = src[i];
        if (i + d < 4096) v += src[i + d];
        dst[i] = v;
      }
      __syncthreads();
      unsigned int* t = src; src = dst; dst = t;
    }
    for (int i = tid; i < 4096; i += 1024) {
      unsigned int s = src[i];
      unsigned int sn = (i < 4095) ? src[i + 1] : 0u;
      if (s >= PRE && sn < PRE) { scal[1] = i; scal[2] = (int)sn; }
    }
    __syncthreads();
  }
  const int cb = scal[1];
  const unsigned int nG = (unsigned int)scal[2];
  __syncthreads();

  // ---- level-2 histogram: within coarse bin, sortable bits [19:8] ----
  for (int i = tid; i < 4096; i += 1024) histA[i] = 0;
  __syncthreads();
  for (int i = tid; i < NANCH; i += 1024) {
    unsigned long long k = kb[i];
    if ((int)(k >> 52) == cb)
      atomicAdd(&histA[(unsigned int)((k >> 40) & 0xFFFull)], 1u);
  }
  __syncthreads();
  {
    unsigned int *src = histA, *dst = histB;
    for (int d = 1; d < 4096; d <<= 1) {
      for (int i = tid; i < 4096; i += 1024) {
        unsigned int v = src[i];
        if (i + d < 4096) v += src[i + d];
        dst[i] = v;
      }
      __syncthreads();
      unsigned int* t = src; src = dst; dst = t;
    }
    unsigned int need2 = PRE - nG;
    for (int i = tid; i < 4096; i += 1024) {
      unsigned int s = src[i];
      unsigned int sn = (i < 4095) ? src[i + 1] : 0u;
      if (s >= need2 && sn < need2) scal[3] = i;
    }
    __syncthreads();
  }
  const unsigned int thrT = ((unsigned int)cb << 20) | ((unsigned int)scal[3] << 8);

  // ---- compaction: wave-aggregated atomic (one atomicAdd per wave-iter) ----
  if (tid == 0) scal[0] = 0;
  __syncthreads();
  for (int i0 = 0; i0 < 90112; i0 += 1024) {   // uniform bound: 88*1024 >= NANCH
    int i = i0 + tid;
    unsigned long long k = (i < NANCH) ? kb[i] : 0ull;
    bool pred_ = (i < NANCH) && ((unsigned int)(k >> 32) >= thrT);
    unsigned long long bal = __ballot(pred_);
    int cnt = __popcll(bal);
    int base = 0;
    if (lane == 0 && cnt) base = atomicAdd(&scal[0], cnt);
    base = __builtin_amdgcn_readfirstlane(base);
    int pos = base + __popcll(bal & ((1ull << lane) - 1ull));
    if (pred_ && pos < SORTN) cand[pos] = k;
  }
  __syncthreads();
  {
    int cnt = scal[0]; if (cnt > SORTN) cnt = SORTN;
    for (int i = tid; i < SORTN; i += 1024)
      if (i >= cnt) cand[i] = 0ull;
  }
  __syncthreads();

  // ---- bitonic sort, descending ----
  for (int k = 2; k <= SORTN; k <<= 1) {
    for (int j = k >> 1; j > 0; j >>= 1) {
      for (int i = tid; i < SORTN; i += 1024) {
        int ixj = i ^ j;
        if (ixj > i) {
          unsigned long long a0 = cand[i], a1 = cand[ixj];
          bool up = (i & k) != 0;
          bool sw = up ? (a0 > a1) : (a0 < a1);
          if (sw) { cand[i] = a1; cand[ixj] = a0; }
        }
      }
      __syncthreads();
    }
  }

  // ---- decode top-6000 boxes to global ----
  const float imh = iminfo[b*3+0], imw = iminfo[b*3+1];
  float4* bg = boxes_g + (size_t)b * PRE;
  for (int s = tid; s < PRE; s += 1024) {
    unsigned long long k = cand[s];
    unsigned int idx = ~(unsigned int)(k & 0xFFFFFFFFull);
    float4 bx = make_float4(0.f, 0.f, 0.f, 0.f);
    if (idx < NANCH) bx = decode_box(pred, anchors, b, (int)idx, imw, imh);
    bg[s] = bx;
  }
  // ---- live mask words to global ----
  const unsigned int liveThr = f2sort(-5.0e8f);
  for (int w = tid; w < NWORD; w += 1024) {
    unsigned int m = 0u;
    for (int k2 = 0; k2 < 32; ++k2) {
      int s = w * 32 + k2;
      if (s < PRE && (unsigned int)(cand[s] >> 32) > liveThr) m |= (1u << k2);
    }
    live_g[b * NWORD + w] = m;
  }
}

__device__ __forceinline__ float iou_f(const float4& a, float areaA, const float4& k2) {
  float xx1 = fmaxf(a.x, k2.x);
  float yy1 = fmaxf(a.y, k2.y);
  float xx2 = fminf(a.z, k2.z);
  float yy2 = fminf(a.w, k2.w);
  float inter = fmaxf(xx2 - xx1 + 1.0f, 0.0f) * fmaxf(yy2 - yy1 + 1.0f, 0.0f);
  float areaK = (k2.z - k2.x + 1.0f) * (k2.w - k2.y + 1.0f);
  return inter / (areaA + areaK - inter);
}

// K3: one 256-thread block per batch; contiguous register-resident boxes;
// ballot+readlane find-first/second; speculative DUAL-PICK per barrier.
__global__ __launch_bounds__(NT, 1) void k_nms(
    const float4* __restrict__ boxes_g,
    const unsigned int* __restrict__ live_g,
    float* __restrict__ out) {
  __shared__ float4 bxs[PRE];          // 96000B, SWZ-indexed
  __shared__ float4 obuf[POST];
  __shared__ int2 wpart[2][NT/64];     // per-wave (first,second) live, dbuf by bt
  const int b = blockIdx.x;
  const int tid = threadIdx.x;
  const int wave = tid >> 6, lane = tid & 63;
  const float4* bg = boxes_g + (size_t)b * PRE;
  for (int i = tid; i < PRE; i += NT) bxs[SWZ(i)] = bg[i];
  __syncthreads();

  // contiguous ownership: thread owns c = tid*KPT + k
  float rx1[KPT], ry1[KPT], rx2[KPT], ry2[KPT];
  unsigned int alive = 0u;
  #pragma unroll
  for (int k = 0; k < KPT; ++k) {
    int c = tid * KPT + k;
    float4 bb = (c < PRE) ? bxs[SWZ(c)] : make_float4(0.f, 0.f, 0.f, 0.f);
    rx1[k] = bb.x; ry1[k] = bb.y; rx2[k] = bb.z; ry2[k] = bb.w;
    unsigned int lv = (c < PRE) ? ((live_g[b * NWORD + (c >> 5)] >> (c & 31)) & 1u) : 0u;
    alive |= lv << k;
  }

  int it = 0, bt = 0;
  while (it < POST) {
    // ---- per-thread first & second live index ----
    unsigned int a2m = alive & (alive - 1u);
    int c1 = tid * KPT + (__ffs(alive) - 1);                  // used only if alive!=0
    int c2 = a2m ? (tid * KPT + (__ffs(a2m) - 1)) : BIGI;
    // ---- wave level: two smallest via ballot + readlane ----
    unsigned long long bal = __ballot(alive != 0u);
    int j1w = BIGI, j2w = BIGI;
    if (bal) {
      int fl1 = __ffsll((unsigned long long)bal) - 1;
      j1w = __builtin_amdgcn_readlane(c1, fl1);
      int ca = __builtin_amdgcn_readlane(c2, fl1);
      unsigned long long bal2 = bal & (bal - 1ull);
      int cb2 = BIGI;
      if (bal2) cb2 = __builtin_amdgcn_readlane(c1, __ffsll((unsigned long long)bal2) - 1);
      j2w = min(ca, cb2);
    }
    if (lane == 0) wpart[bt & 1][wave] = make_int2(j1w, j2w);
    __syncthreads();
    // ---- block level: merge 4 (first,second) pairs ----
    int j1 = BIGI, j2 = BIGI;
    #pragma unroll
    for (int w = 0; w < NT/64; ++w) {
      int2 p = wpart[bt & 1][w];
      if (p.x < j1) { j2 = min(j1, p.y); j1 = p.x; }
      else          { j2 = min(j2, p.x); }
    }
    if (j1 == BIGI) break;
    float4 bj1 = bxs[SWZ(j1)];
    int j2r = (j2 == BIGI) ? j1 : j2;
    float4 bj2 = bxs[SWZ(j2r)];
    float A1 = (bj1.z - bj1.x + 1.0f) * (bj1.w - bj1.y + 1.0f);
    float A2 = (bj2.z - bj2.x + 1.0f) * (bj2.w - bj2.y + 1.0f);
    // speculation check (uniform across threads)
    float iou12 = iou_f(bj1, A1, bj2);
    bool ok2 = (j2 != BIGI) && (it + 1 < POST) && (iou12 <= NMS_T);
    if (tid == 0) {
      obuf[it] = bj1;
      if (ok2) obuf[it + 1] = bj2;
    }
    // ---- register-only dual suppression sweep ----
    if (alive) {
      unsigned int okm = ok2 ? 0xFFFFFFFFu : 0u;
      #pragma unroll
      for (int k = 0; k < KPT; ++k) {
        float4 bk = make_float4(rx1[k], ry1[k], rx2[k], ry2[k]);
        unsigned int s1 = (unsigned int)(iou_f(bj1, A1, bk) > NMS_T);
        unsigned int s2 = (unsigned int)(iou_f(bj2, A2, bk) > NMS_T) & okm;
        alive &= ~((s1 | s2) << k);
      }
    }
    it += ok2 ? 2 : 1;
    ++bt;
  }
  // ---- fill remaining picks with zeros ----
  for (int k = it + tid; k < POST; k += NT) obuf[k] = make_float4(0.f, 0.f, 0.f, 0.f);
  __syncthreads();
  // ---- coalesced output write: [b][POST][5] = (b, x1, y1, x2, y2) ----
  float* ob = out + (size_t)b * POST * 5;
  for (int i = tid; i < POST * 5; i += NT) {
    int row = i / 5, col = i - row * 5;
    float v;
    if (col == 0) v = (float)b;
    else {
      float4 bb = obuf[row];
      v = (col == 1) ? bb.x : (col == 2) ? bb.y : (col == 3) ? bb.z : bb.w;
    }
    ob[i] = v;
  }
}

extern "C" void kernel_launch(void* const* d_in, const int* in_sizes, int n_in,
                              void* d_out, int out_size, void* d_ws, size_t ws_size,
                              hipStream_t stream) {
  const float* cls     = (const float*)d_in[0];
  const float* pred    = (const float*)d_in[1];
  const float* iminfo  = (const float*)d_in[2];
  const float* anchors = (const float*)d_in[3];
  float* out = (float*)d_out;

  unsigned char* ws = (unsigned char*)d_ws;
  unsigned long long* keys = (unsigned long long*)ws;                 // 23,040,000 B
  float4* boxes_g = (float4*)(ws + (size_t)NB * NANCH * 8);           //  3,072,000 B
  unsigned int* live_g = (unsigned int*)(ws + (size_t)NB * NANCH * 8
                                            + (size_t)NB * PRE * 16); //     24,064 B

  int total = NB * NANCH;
  int blocks = (total + 255) / 256;
  k_decode<<<blocks, 256, 0, stream>>>(cls, pred, iminfo, anchors, keys);
  k_select<<<NB, 1024, 0, stream>>>(keys, pred, iminfo, anchors, boxes_g, live_g);
  k_nms<<<NB, NT, 0, stream>>>(boxes_g, live_g, out);
}

// Round 7
// 434.175 us; speedup vs baseline: 1.6340x; 1.6340x over previous
//
#include <hip/hip_runtime.h>

#define NB 32
#define NA 9
#define FH 100
#define FW 100
#define HWSZ (FH*FW)          // 10000
#define NANCH (HWSZ*NA)       // 90000
#define PRE 6000
#define POST 300
#define SORTN 8192
#define NWORD 188             // ceil(6000/32)
#define NEGV -1000000000.0f
#define NMS_T 0.7f
#define NCHUNK ((PRE + 63) / 64)   // 94

__device__ __forceinline__ unsigned int f2sort(float f) {
  unsigned int u = __float_as_uint(f);
  return (u & 0x80000000u) ? ~u : (u | 0x80000000u);
}

// Decode one anchor's clipped box. i in [0, NANCH): i = (h*FW + w)*NA + a
__device__ __forceinline__ float4 decode_box(const float* __restrict__ pred,
                                             const float* __restrict__ anchors,
                                             int b, int i, float imw, float imh) {
  int hw = i / NA; int a = i - hw * NA;
  int h = hw / FW; int w = hw - h * FW;
  float sx = (float)(w * 16);
  float sy = (float)(h * 16);
  float ax1 = anchors[a*4+0] + sx, ay1 = anchors[a*4+1] + sy;
  float ax2 = anchors[a*4+2] + sx, ay2 = anchors[a*4+3] + sy;
  float wa = ax2 - ax1 + 1.0f, ha = ay2 - ay1 + 1.0f;
  float cxa = ax1 + 0.5f*(wa - 1.0f), cya = ay1 + 0.5f*(ha - 1.0f);
  size_t base = (((size_t)b*36 + a*4)*FH + h)*FW + w;
  float dx = pred[base];
  float dy = pred[base + HWSZ];
  float dw = pred[base + 2*HWSZ];
  float dh = pred[base + 3*HWSZ];
  float cx = dx*wa + cxa, cy = dy*ha + cya;
  float pw = expf(dw)*wa, ph = expf(dh)*ha;
  float x1 = fminf(fmaxf(cx - 0.5f*(pw - 1.0f), 0.0f), imw - 1.0f);
  float y1 = fminf(fmaxf(cy - 0.5f*(ph - 1.0f), 0.0f), imh - 1.0f);
  float x2 = fminf(fmaxf(cx + 0.5f*(pw - 1.0f), 0.0f), imw - 1.0f);
  float y2 = fminf(fmaxf(cy + 0.5f*(ph - 1.0f), 0.0f), imh - 1.0f);
  return make_float4(x1, y1, x2, y2);
}

// K1: per-anchor score with min-size filter -> sortable key
__global__ void k_decode(const float* __restrict__ cls,
                         const float* __restrict__ pred,
                         const float* __restrict__ iminfo,
                         const float* __restrict__ anchors,
                         unsigned long long* __restrict__ keys) {
  int gid = blockIdx.x * blockDim.x + threadIdx.x;
  if (gid >= NB * NANCH) return;
  int b = gid / NANCH;
  int i = gid - b * NANCH;
  int hw = i / NA; int a = i - hw * NA;
  int h = hw / FW; int w = hw - h * FW;
  float score = cls[(((size_t)b*18 + 9 + a)*FH + h)*FW + w];
  float imh = iminfo[b*3+0], imw = iminfo[b*3+1], sc = iminfo[b*3+2];
  float4 bx = decode_box(pred, anchors, b, i, imw, imh);
  float msz = 16.0f * sc;
  bool keep = ((bx.z - bx.x + 1.0f) >= msz) && ((bx.w - bx.y + 1.0f) >= msz);
  float sf = keep ? score : NEGV;
  unsigned long long key = ((unsigned long long)f2sort(sf) << 32)
                         | (unsigned int)(~(unsigned int)i);
  keys[(size_t)b * NANCH + i] = key;
}

// K2: per-batch block: radix-threshold select -> compact -> bitonic sort ->
// decode top-6000 boxes + live mask to GLOBAL
#define SMEM_BYTES (65536 + 16384 + 16384 + 64)
__global__ __launch_bounds__(1024, 1) void k_select(
    const unsigned long long* __restrict__ keys,
    const float* __restrict__ pred,
    const float* __restrict__ iminfo,
    const float* __restrict__ anchors,
    float4* __restrict__ boxes_g,
    unsigned int* __restrict__ live_g) {
  __shared__ __align__(16) unsigned char smemRaw[SMEM_BYTES];
  unsigned long long* cand = (unsigned long long*)smemRaw;            // [8192] 65536B
  unsigned int* histA = (unsigned int*)(smemRaw + 65536);             // [4096]
  unsigned int* histB = (unsigned int*)(smemRaw + 81920);             // [4096]
  int* scal = (int*)(smemRaw + 98304);                                // [16]

  const int b = blockIdx.x;
  const int tid = threadIdx.x;
  const int lane = tid & 63;
  const unsigned long long* kb = keys + (size_t)b * NANCH;

  // ---- level-1 histogram: sortable bits [31:20] ----
  for (int i = tid; i < 4096; i += 1024) histA[i] = 0;
  __syncthreads();
  for (int i = tid; i < NANCH; i += 1024)
    atomicAdd(&histA[(unsigned int)(kb[i] >> 52)], 1u);
  __syncthreads();
  {
    unsigned int *src = histA, *dst = histB;
    for (int d = 1; d < 4096; d <<= 1) {
      for (int i = tid; i < 4096; i += 1024) {
        unsigned int v = src[i];
        if (i + d < 4096) v += src[i + d];
        dst[i] = v;
      }
      __syncthreads();
      unsigned int* t = src; src = dst; dst = t;
    }
    for (int i = tid; i < 4096; i += 1024) {
      unsigned int s = src[i];
      unsigned int sn = (i < 4095) ? src[i + 1] : 0u;
      if (s >= PRE && sn < PRE) { scal[1] = i; scal[2] = (int)sn; }
    }
    __syncthreads();
  }
  const int cb = scal[1];
  const unsigned int nG = (unsigned int)scal[2];
  __syncthreads();

  // ---- level-2 histogram: within coarse bin, sortable bits [19:8] ----
  for (int i = tid; i < 4096; i += 1024) histA[i] = 0;
  __syncthreads();
  for (int i = tid; i < NANCH; i += 1024) {
    unsigned long long k = kb[i];
    if ((int)(k >> 52) == cb)
      atomicAdd(&histA[(unsigned int)((k >> 40) & 0xFFFull)], 1u);
  }
  __syncthreads();
  {
    unsigned int *src = histA, *dst = histB;
    for (int d = 1; d < 4096; d <<= 1) {
      for (int i = tid; i < 4096; i += 1024) {
        unsigned int v = src[i];
        if (i + d < 4096) v += src[i + d];
        dst[i] = v;
      }
      __syncthreads();
      unsigned int* t = src; src = dst; dst = t;
    }
    unsigned int need2 = PRE - nG;
    for (int i = tid; i < 4096; i += 1024) {
      unsigned int s = src[i];
      unsigned int sn = (i < 4095) ? src[i + 1] : 0u;
      if (s >= need2 && sn < need2) scal[3] = i;
    }
    __syncthreads();
  }
  const unsigned int thrT = ((unsigned int)cb << 20) | ((unsigned int)scal[3] << 8);

  // ---- compaction: wave-aggregated atomic (one atomicAdd per wave-iter) ----
  if (tid == 0) scal[0] = 0;
  __syncthreads();
  for (int i0 = 0; i0 < 90112; i0 += 1024) {   // uniform bound: 88*1024 >= NANCH
    int i = i0 + tid;
    unsigned long long k = (i < NANCH) ? kb[i] : 0ull;
    bool pred_ = (i < NANCH) && ((unsigned int)(k >> 32) >= thrT);
    unsigned long long bal = __ballot(pred_);
    int cnt = __popcll(bal);
    int base = 0;
    if (lane == 0 && cnt) base = atomicAdd(&scal[0], cnt);
    base = __builtin_amdgcn_readfirstlane(base);
    int pos = base + __popcll(bal & ((1ull << lane) - 1ull));
    if (pred_ && pos < SORTN) cand[pos] = k;
  }
  __syncthreads();
  {
    int cnt = scal[0]; if (cnt > SORTN) cnt = SORTN;
    for (int i = tid; i < SORTN; i += 1024)
      if (i >= cnt) cand[i] = 0ull;
  }
  __syncthreads();

  // ---- bitonic sort, descending ----
  for (int k = 2; k <= SORTN; k <<= 1) {
    for (int j = k >> 1; j > 0; j >>= 1) {
      for (int i = tid; i < SORTN; i += 1024) {
        int ixj = i ^ j;
        if (ixj > i) {
          unsigned long long a0 = cand[i], a1 = cand[ixj];
          bool up = (i & k) != 0;
          bool sw = up ? (a0 > a1) : (a0 < a1);
          if (sw) { cand[i] = a1; cand[ixj] = a0; }
        }
      }
      __syncthreads();
    }
  }

  // ---- decode top-6000 boxes to global ----
  const float imh = iminfo[b*3+0], imw = iminfo[b*3+1];
  float4* bg = boxes_g + (size_t)b * PRE;
  for (int s = tid; s < PRE; s += 1024) {
    unsigned long long k = cand[s];
    unsigned int idx = ~(unsigned int)(k & 0xFFFFFFFFull);
    float4 bx = make_float4(0.f, 0.f, 0.f, 0.f);
    if (idx < NANCH) bx = decode_box(pred, anchors, b, (int)idx, imw, imh);
    bg[s] = bx;
  }
  // ---- live mask words to global ----
  const unsigned int liveThr = f2sort(-5.0e8f);
  for (int w = tid; w < NWORD; w += 1024) {
    unsigned int m = 0u;
    for (int k2 = 0; k2 < 32; ++k2) {
      int s = w * 32 + k2;
      if (s < PRE && (unsigned int)(cand[s] >> 32) > liveThr) m |= (1u << k2);
    }
    live_g[b * NWORD + w] = m;
  }
}

// K3: ONE WAVE per batch, accepted-list greedy NMS — zero barriers in the
// main loop. Candidate c accepted iff live AND IoU<=T vs all prior accepts.
__global__ __launch_bounds__(64, 1) void k_nms(
    const float4* __restrict__ boxes_g,
    const unsigned int* __restrict__ live_g,
    float* __restrict__ out) {
  __shared__ float4 accB[POST];        // accepted boxes, in pick order (4.8KB)
  const int b = blockIdx.x;
  const int lane = threadIdx.x;
  const float4* bg = boxes_g + (size_t)b * PRE;
  const unsigned int* lg = live_g + b * NWORD;

  // prefetch chunk 0
  int c = lane;
  bool okC = ((lg[c >> 5] >> (c & 31)) & 1u) != 0u;
  float4 bcC = bg[c];

  int nAcc = 0;
  for (int g = 0; g < NCHUNK && nAcc < POST; ++g) {
    // issue prefetch for chunk g+1 (hidden under this chunk's processing)
    bool okN = false;
    float4 bcN = make_float4(0.f, 0.f, 0.f, 0.f);
    if (g + 1 < NCHUNK) {
      int cn = (g + 1) * 64 + lane;
      if (cn < PRE) {
        okN = ((lg[cn >> 5] >> (cn & 31)) & 1u) != 0u;
        bcN = bg[cn];
      }
    }
    bool ok = okC;
    float4 bc = bcC;
    float areaC = (bc.z - bc.x + 1.0f) * (bc.w - bc.y + 1.0f);

    // ---- test against accepted list, 8-blocked with ballot early-out ----
    for (int t = 0; t < nAcc; t += 8) {
      if (__ballot(ok) == 0ull) break;
      int te = (t + 8 < nAcc) ? (t + 8) : nAcc;
      for (int tt = t; tt < te; ++tt) {
        float4 ba = accB[tt];                 // LDS broadcast
        float areaA = (ba.z - ba.x + 1.0f) * (ba.w - ba.y + 1.0f);
        float xx1 = fmaxf(ba.x, bc.x);
        float yy1 = fmaxf(ba.y, bc.y);
        float xx2 = fminf(ba.z, bc.z);
        float yy2 = fminf(ba.w, bc.w);
        float inter = fmaxf(xx2 - xx1 + 1.0f, 0.0f) * fmaxf(yy2 - yy1 + 1.0f, 0.0f);
        float iou = inter / (areaA + areaC - inter);
        ok = ok && (iou <= NMS_T);
      }
    }

    // ---- in-chunk sequential resolution: ballot + readlane ----
    unsigned long long bal = __ballot(ok);
    while (bal != 0ull && nAcc < POST) {
      int fl = __ffsll(bal) - 1;              // wave-uniform (SGPR)
      float ax1 = __int_as_float(__builtin_amdgcn_readlane(__float_as_int(bc.x), fl));
      float ay1 = __int_as_float(__builtin_amdgcn_readlane(__float_as_int(bc.y), fl));
      float ax2 = __int_as_float(__builtin_amdgcn_readlane(__float_as_int(bc.z), fl));
      float ay2 = __int_as_float(__builtin_amdgcn_readlane(__float_as_int(bc.w), fl));
      if (lane == 0) accB[nAcc] = make_float4(ax1, ay1, ax2, ay2);
      ++nAcc;
      if (ok) {
        if (lane == fl) ok = false;           // accepted; no longer candidate
        else if (lane > fl) {
          float areaA = (ax2 - ax1 + 1.0f) * (ay2 - ay1 + 1.0f);
          float xx1 = fmaxf(ax1, bc.x);
          float yy1 = fmaxf(ay1, bc.y);
          float xx2 = fminf(ax2, bc.z);
          float yy2 = fminf(ay2, bc.w);
          float inter = fmaxf(xx2 - xx1 + 1.0f, 0.0f) * fmaxf(yy2 - yy1 + 1.0f, 0.0f);
          float iou = inter / (areaA + areaC - inter);
          if (iou > NMS_T) ok = false;
        }
      }
      bal = __ballot(ok);
    }

    okC = okN; bcC = bcN;
  }

  // ---- output: [b][POST][5] = (b, x1, y1, x2, y2); rows >= nAcc zeroed ----
  float* ob = out + (size_t)b * POST * 5;
  for (int i = lane; i < POST * 5; i += 64) {
    int row = i / 5, col = i - row * 5;
    float v = 0.f;
    if (col == 0) v = (float)b;
    else if (row < nAcc) {
      float4 bb = accB[row];
      v = (col == 1) ? bb.x : (col == 2) ? bb.y : (col == 3) ? bb.z : bb.w;
    }
    ob[i] = v;
  }
}

extern "C" void kernel_launch(void* const* d_in, const int* in_sizes, int n_in,
                              void* d_out, int out_size, void* d_ws, size_t ws_size,
                              hipStream_t stream) {
  const float* cls     = (const float*)d_in[0];
  const float* pred    = (const float*)d_in[1];
  const float* iminfo  = (const float*)d_in[2];
  const float* anchors = (const float*)d_in[3];
  float* out = (float*)d_out;

  unsigned char* ws = (unsigned char*)d_ws;
  unsigned long long* keys = (unsigned long long*)ws;                 // 23,040,000 B
  float4* boxes_g = (float4*)(ws + (size_t)NB * NANCH * 8);           //  3,072,000 B
  unsigned int* live_g = (unsigned int*)(ws + (size_t)NB * NANCH * 8
                                            + (size_t)NB * PRE * 16); //     24,064 B

  int total = NB * NANCH;
  int blocks = (total + 255) / 256;
  k_decode<<<blocks, 256, 0, stream>>>(cls, pred, iminfo, anchors, keys);
  k_select<<<NB, 1024, 0, stream>>>(keys, pred, iminfo, anchors, boxes_g, live_g);
  k_nms<<<NB, 64, 0, stream>>>(boxes_g, live_g, out);
}

// Round 8
// 387.342 us; speedup vs baseline: 1.8315x; 1.1209x over previous
//
#include <hip/hip_runtime.h>

#define NB 32
#define NA 9
#define FH 100
#define FW 100
#define HWSZ (FH*FW)          // 10000
#define NANCH (HWSZ*NA)       // 90000
#define PRE 6000
#define POST 300
#define SORTN 8192
#define NEGV -1000000000.0f
#define NMS_T 0.7f
#define NCHUNK ((PRE + 63) / 64)   // 94

typedef unsigned long long u64;
typedef unsigned int u32;

__device__ __forceinline__ u32 f2sort(float f) {
  u32 u = __float_as_uint(f);
  return (u & 0x80000000u) ? ~u : (u | 0x80000000u);
}

// Decode one anchor's clipped box. i in [0, NANCH): i = (h*FW + w)*NA + a
__device__ __forceinline__ float4 decode_box(const float* __restrict__ pred,
                                             const float* __restrict__ anchors,
                                             int b, int i, float imw, float imh) {
  int hw = i / NA; int a = i - hw * NA;
  int h = hw / FW; int w = hw - h * FW;
  float sx = (float)(w * 16);
  float sy = (float)(h * 16);
  float ax1 = anchors[a*4+0] + sx, ay1 = anchors[a*4+1] + sy;
  float ax2 = anchors[a*4+2] + sx, ay2 = anchors[a*4+3] + sy;
  float wa = ax2 - ax1 + 1.0f, ha = ay2 - ay1 + 1.0f;
  float cxa = ax1 + 0.5f*(wa - 1.0f), cya = ay1 + 0.5f*(ha - 1.0f);
  size_t base = (((size_t)b*36 + a*4)*FH + h)*FW + w;
  float dx = pred[base];
  float dy = pred[base + HWSZ];
  float dw = pred[base + 2*HWSZ];
  float dh = pred[base + 3*HWSZ];
  float cx = dx*wa + cxa, cy = dy*ha + cya;
  float pw = expf(dw)*wa, ph = expf(dh)*ha;
  float x1 = fminf(fmaxf(cx - 0.5f*(pw - 1.0f), 0.0f), imw - 1.0f);
  float y1 = fminf(fmaxf(cy - 0.5f*(ph - 1.0f), 0.0f), imh - 1.0f);
  float x2 = fminf(fmaxf(cx + 0.5f*(pw - 1.0f), 0.0f), imw - 1.0f);
  float y2 = fminf(fmaxf(cy + 0.5f*(ph - 1.0f), 0.0f), imh - 1.0f);
  return make_float4(x1, y1, x2, y2);
}

// K1: per-anchor score with min-size filter -> sortable key
__global__ void k_decode(const float* __restrict__ cls,
                         const float* __restrict__ pred,
                         const float* __restrict__ iminfo,
                         const float* __restrict__ anchors,
                         u64* __restrict__ keys) {
  int gid = blockIdx.x * blockDim.x + threadIdx.x;
  if (gid >= NB * NANCH) return;
  int b = gid / NANCH;
  int i = gid - b * NANCH;
  int hw = i / NA; int a = i - hw * NA;
  int h = hw / FW; int w = hw - h * FW;
  float score = cls[(((size_t)b*18 + 9 + a)*FH + h)*FW + w];
  float imh = iminfo[b*3+0], imw = iminfo[b*3+1], sc = iminfo[b*3+2];
  float4 bx = decode_box(pred, anchors, b, i, imw, imh);
  float msz = 16.0f * sc;
  bool keep = ((bx.z - bx.x + 1.0f) >= msz) && ((bx.w - bx.y + 1.0f) >= msz);
  float sf = keep ? score : NEGV;
  u64 key = ((u64)f2sort(sf) << 32) | (u32)(~(u32)i);
  keys[(size_t)b * NANCH + i] = key;
}

// wave-0 suffix cut search over 4096-bin histogram:
// finds cutBin = max b with suffix(b) >= target, and nAfter = suffix(cutBin+1).
__device__ __forceinline__ void w0_cut(unsigned int* hist, u32 target, int lane,
                                       int* cutBin, u32* nAfter) {
  u32 cs = 0;
  int cb = lane * 64;
  for (int i = 0; i < 64; ++i) cs += hist[cb + ((i + lane) & 63)];
  u32 suf = cs;
  #pragma unroll
  for (int d = 1; d < 64; d <<= 1) {
    u32 o = __shfl_down(suf, (unsigned)d, 64);
    suf += (lane < 64 - d) ? o : 0u;
  }
  u64 m1 = __ballot(suf >= target);
  int L = 63 - __clzll(m1);
  u32 nAb = (L < 63) ? (u32)__builtin_amdgcn_readlane((int)suf, L + 1) : 0u;
  u32 fs = hist[L * 64 + lane];
  #pragma unroll
  for (int d = 1; d < 64; d <<= 1) {
    u32 o = __shfl_down(fs, (unsigned)d, 64);
    fs += (lane < 64 - d) ? o : 0u;
  }
  fs += nAb;
  u64 m2 = __ballot(fs >= target);
  int fb = 63 - __clzll(m2);
  *cutBin = L * 64 + fb;
  *nAfter = (fb < 63) ? (u32)__builtin_amdgcn_readlane((int)fs, fb + 1) : nAb;
}

#define CEX(A,B,UP) { if ((UP) ? ((A) > (B)) : ((A) < (B))) { u64 _t=(A); (A)=(B); (B)=_t; } }

// K2: fused select (hist+cut+compact+sort) + accepted-list NMS + output.
// LDS layout (bytes): cand[8192]u64 @0, hist[4096]u32 @65536,
// accB[300]float4 @81920, accA[300]f @86720, aLds[36]f @87920, scal @88064.
#define SMEM_BYTES 88192
__global__ __launch_bounds__(1024, 1) void k_fused(
    const u64* __restrict__ keys,
    const float* __restrict__ pred,
    const float* __restrict__ iminfo,
    const float* __restrict__ anchors,
    float* __restrict__ out) {
  __shared__ __align__(16) unsigned char smemRaw[SMEM_BYTES];
  u64* cand = (u64*)smemRaw;
  volatile u64* vc = (volatile u64*)smemRaw;
  u32* hist = (u32*)(smemRaw + 65536);
  float4* accB = (float4*)(smemRaw + 81920);
  float* accA = (float*)(smemRaw + 86720);
  float* aL = (float*)(smemRaw + 87920);
  int* scal = (int*)(smemRaw + 88064);

  const int b = blockIdx.x;
  const int tid = threadIdx.x;
  const int wave = tid >> 6, lane = tid & 63;
  const u64* kb = keys + (size_t)b * NANCH;
  const u32 liveThr = f2sort(-5.0e8f);

  if (tid < 36) aL[tid] = anchors[tid];
  // ---- level-1 histogram: sortable bits [31:20] ----
  for (int i = tid; i < 4096; i += 1024) hist[i] = 0;
  __syncthreads();
  for (int i = tid; i < NANCH; i += 1024)
    atomicAdd(&hist[(u32)(kb[i] >> 52)], 1u);
  __syncthreads();
  if (wave == 0) {
    int cb; u32 nAf;
    w0_cut(hist, PRE, lane, &cb, &nAf);
    if (lane == 0) { scal[1] = cb; scal[2] = (int)nAf; }
  }
  __syncthreads();
  const int cb1 = scal[1];
  const u32 nG = (u32)scal[2];
  __syncthreads();

  // ---- level-2 histogram within coarse bin: bits [19:8] ----
  for (int i = tid; i < 4096; i += 1024) hist[i] = 0;
  __syncthreads();
  for (int i = tid; i < NANCH; i += 1024) {
    u64 k = kb[i];
    if ((int)(k >> 52) == cb1)
      atomicAdd(&hist[(u32)((k >> 40) & 0xFFFull)], 1u);
  }
  __syncthreads();
  if (wave == 0) {
    int cb2; u32 nAf2;
    w0_cut(hist, PRE - nG, lane, &cb2, &nAf2);
    if (lane == 0) scal[3] = cb2;
  }
  __syncthreads();
  const u32 thrT = ((u32)cb1 << 20) | ((u32)scal[3] << 8);

  // ---- compaction: wave-aggregated atomic ----
  if (tid == 0) scal[0] = 0;
  __syncthreads();
  for (int i0 = 0; i0 < 90112; i0 += 1024) {
    int i = i0 + tid;
    u64 k = (i < NANCH) ? kb[i] : 0ull;
    bool pred_ = (i < NANCH) && ((u32)(k >> 32) >= thrT);
    u64 bal = __ballot(pred_);
    int cnt = __popcll(bal);
    int base = 0;
    if (lane == 0 && cnt) base = atomicAdd(&scal[0], cnt);
    base = __builtin_amdgcn_readfirstlane(base);
    int pos = base + __popcll(bal & ((1ull << lane) - 1ull));
    if (pred_ && pos < SORTN) cand[pos] = k;
  }
  __syncthreads();
  {
    int cnt = scal[0]; if (cnt > SORTN) cnt = SORTN;
    for (int i = tid; i < SORTN; i += 1024)
      if (i >= cnt) cand[i] = 0ull;
  }
  __syncthreads();

  // ---- bitonic sort, descending; wave-segment barrier-free for j<512 ----
  {
    // initial fused round: k=2,4,8 entirely in registers on own 8 elements
    int tb = tid * 8;
    u64 e0=vc[tb+0], e1=vc[tb+1], e2=vc[tb+2], e3=vc[tb+3];
    u64 e4=vc[tb+4], e5=vc[tb+5], e6=vc[tb+6], e7=vc[tb+7];
    bool u8b = (tb & 8) != 0;
    CEX(e0,e1,false) CEX(e2,e3,true) CEX(e4,e5,false) CEX(e6,e7,true)       // k=2
    CEX(e0,e2,false) CEX(e1,e3,false) CEX(e4,e6,true) CEX(e5,e7,true)       // k=4 j=2
    CEX(e0,e1,false) CEX(e2,e3,false) CEX(e4,e5,true) CEX(e6,e7,true)       // k=4 j=1
    CEX(e0,e4,u8b) CEX(e1,e5,u8b) CEX(e2,e6,u8b) CEX(e3,e7,u8b)             // k=8 j=4
    CEX(e0,e2,u8b) CEX(e1,e3,u8b) CEX(e4,e6,u8b) CEX(e5,e7,u8b)             // k=8 j=2
    CEX(e0,e1,u8b) CEX(e2,e3,u8b) CEX(e4,e5,u8b) CEX(e6,e7,u8b)             // k=8 j=1
    vc[tb+0]=e0; vc[tb+1]=e1; vc[tb+2]=e2; vc[tb+3]=e3;
    vc[tb+4]=e4; vc[tb+5]=e5; vc[tb+6]=e6; vc[tb+7]=e7;
  }
  for (int k = 16; k <= SORTN; k <<= 1) {
    int j = k >> 1;
    for (; j >= 512; j >>= 1) {               // cross-wave steps (barriered)
      __syncthreads();
      for (int m = tid; m < SORTN/2; m += 1024) {
        int i = ((m & ~(j-1)) << 1) | (m & (j-1));
        int x = i | j;
        u64 a0 = vc[i], a1 = vc[x];
        bool up = (i & k) != 0;
        if (up ? (a0 > a1) : (a0 < a1)) { vc[i] = a1; vc[x] = a0; }
      }
    }
    if (k >= 1024) __syncthreads();           // transition to intra-wave
    for (; j >= 8; j >>= 1) {                 // intra-wave steps (no barrier)
      int base = wave * 512;
      for (int m = lane; m < 256; m += 64) {
        int lo = ((m & ~(j-1)) << 1) | (m & (j-1));
        int i = base + lo, x = i | j;
        u64 a0 = vc[i], a1 = vc[x];
        bool up = (i & k) != 0;
        if (up ? (a0 > a1) : (a0 < a1)) { vc[i] = a1; vc[x] = a0; }
      }
    }
    {                                          // fused j=4,2,1 register tail
      int tb = tid * 8;
      u64 e0=vc[tb+0], e1=vc[tb+1], e2=vc[tb+2], e3=vc[tb+3];
      u64 e4=vc[tb+4], e5=vc[tb+5], e6=vc[tb+6], e7=vc[tb+7];
      bool up = (tb & k) != 0;
      CEX(e0,e4,up) CEX(e1,e5,up) CEX(e2,e6,up) CEX(e3,e7,up)
      CEX(e0,e2,up) CEX(e1,e3,up) CEX(e4,e6,up) CEX(e5,e7,up)
      CEX(e0,e1,up) CEX(e2,e3,up) CEX(e4,e5,up) CEX(e6,e7,up)
      vc[tb+0]=e0; vc[tb+1]=e1; vc[tb+2]=e2; vc[tb+3]=e3;
      vc[tb+4]=e4; vc[tb+5]=e5; vc[tb+6]=e6; vc[tb+7]=e7;
    }
  }
  __syncthreads();

  // ---- NMS (wave 0): accepted-list, lazy per-chunk decode, prefetched ----
  const float imh = iminfo[b*3+0], imw = iminfo[b*3+1];
  if (wave == 0) {
    int idxC; bool liveC; float dxC, dyC, dwC, dhC;
    {
      u64 k0 = cand[lane];
      liveC = ((u32)(k0 >> 32) > liveThr) && (lane < PRE);
      idxC = (int)(~(u32)k0);
      bool v = (u32)idxC < (u32)NANCH;
      liveC = liveC && v;
      int id = v ? idxC : 0;
      int hw = id / NA; int a = id - hw * NA;
      int h = hw / FW; int w = hw - h * FW;
      size_t base = (((size_t)b*36 + a*4)*FH + h)*FW + w;
      dxC = pred[base]; dyC = pred[base + HWSZ];
      dwC = pred[base + 2*HWSZ]; dhC = pred[base + 3*HWSZ];
    }
    int nAcc = 0;
    for (int g = 0; g < NCHUNK && nAcc < POST; ++g) {
      // finish decode of chunk g
      float4 bc; float areaC; bool ok = liveC;
      {
        int id = ((u32)idxC < (u32)NANCH) ? idxC : 0;
        int hw = id / NA; int a = id - hw * NA;
        int h = hw / FW; int w = hw - h * FW;
        float sx = (float)(w * 16), sy = (float)(h * 16);
        float ax1 = aL[a*4+0] + sx, ay1 = aL[a*4+1] + sy;
        float ax2 = aL[a*4+2] + sx, ay2 = aL[a*4+3] + sy;
        float wa = ax2 - ax1 + 1.0f, ha = ay2 - ay1 + 1.0f;
        float cxa = ax1 + 0.5f*(wa - 1.0f), cya = ay1 + 0.5f*(ha - 1.0f);
        float cx = dxC*wa + cxa, cy = dyC*ha + cya;
        float pw = expf(dwC)*wa, ph = expf(dhC)*ha;
        bc.x = fminf(fmaxf(cx - 0.5f*(pw - 1.0f), 0.0f), imw - 1.0f);
        bc.y = fminf(fmaxf(cy - 0.5f*(ph - 1.0f), 0.0f), imh - 1.0f);
        bc.z = fminf(fmaxf(cx + 0.5f*(pw - 1.0f), 0.0f), imw - 1.0f);
        bc.w = fminf(fmaxf(cy + 0.5f*(ph - 1.0f), 0.0f), imh - 1.0f);
        areaC = (bc.z - bc.x + 1.0f) * (bc.w - bc.y + 1.0f);
      }
      // issue prefetch for chunk g+1
      int idxN = 0; bool liveN = false;
      float dxN = 0.f, dyN = 0.f, dwN = 0.f, dhN = 0.f;
      if (g + 1 < NCHUNK) {
        int cn = (g + 1) * 64 + lane;
        u64 kn = cand[cn];
        liveN = ((u32)(kn >> 32) > liveThr) && (cn < PRE);
        idxN = (int)(~(u32)kn);
        bool v = (u32)idxN < (u32)NANCH;
        liveN = liveN && v;
        int id = v ? idxN : 0;
        int hw = id / NA; int a = id - hw * NA;
        int h = hw / FW; int w = hw - h * FW;
        size_t nb = (((size_t)b*36 + a*4)*FH + h)*FW + w;
        dxN = pred[nb]; dyN = pred[nb + HWSZ];
        dwN = pred[nb + 2*HWSZ]; dhN = pred[nb + 3*HWSZ];
      }
      // test vs accepted list (8-blocked, ballot early-out)
      for (int t0 = 0; t0 < nAcc; t0 += 8) {
        if (__ballot(ok) == 0ull) break;
        int te = (t0 + 8 < nAcc) ? (t0 + 8) : nAcc;
        for (int tt = t0; tt < te; ++tt) {
          float4 ba = accB[tt];
          float aA = accA[tt];
          float xx1 = fmaxf(ba.x, bc.x);
          float yy1 = fmaxf(ba.y, bc.y);
          float xx2 = fminf(ba.z, bc.z);
          float yy2 = fminf(ba.w, bc.w);
          float inter = fmaxf(xx2 - xx1 + 1.0f, 0.0f) * fmaxf(yy2 - yy1 + 1.0f, 0.0f);
          float iou = inter / (aA + areaC - inter);
          ok = ok && (iou <= NMS_T);
        }
      }
      // in-chunk sequential resolution
      u64 bal = __ballot(ok);
      while (bal != 0ull && nAcc < POST) {
        int fl = __ffsll(bal) - 1;
        float ax1 = __int_as_float(__builtin_amdgcn_readlane(__float_as_int(bc.x), fl));
        float ay1 = __int_as_float(__builtin_amdgcn_readlane(__float_as_int(bc.y), fl));
        float ax2 = __int_as_float(__builtin_amdgcn_readlane(__float_as_int(bc.z), fl));
        float ay2 = __int_as_float(__builtin_amdgcn_readlane(__float_as_int(bc.w), fl));
        float aA = (ax2 - ax1 + 1.0f) * (ay2 - ay1 + 1.0f);
        if (lane == 0) { accB[nAcc] = make_float4(ax1, ay1, ax2, ay2); accA[nAcc] = aA; }
        ++nAcc;
        if (ok) {
          if (lane == fl) ok = false;
          else if (lane > fl) {
            float xx1 = fmaxf(ax1, bc.x);
            float yy1 = fmaxf(ay1, bc.y);
            float xx2 = fminf(ax2, bc.z);
            float yy2 = fminf(ay2, bc.w);
            float inter = fmaxf(xx2 - xx1 + 1.0f, 0.0f) * fmaxf(yy2 - yy1 + 1.0f, 0.0f);
            float iou = inter / (aA + areaC - inter);
            if (iou > NMS_T) ok = false;
          }
        }
        bal = __ballot(ok);
      }
      idxC = idxN; liveC = liveN;
      dxC = dxN; dyC = dyN; dwC = dwN; dhC = dhN;
    }
    if (lane == 0) scal[4] = nAcc;
  }
  __syncthreads();

  // ---- output: [b][POST][5] = (b, x1, y1, x2, y2); rows >= nAcc zeroed ----
  const int nAcc = scal[4];
  float* ob = out + (size_t)b * POST * 5;
  for (int i = tid; i < POST * 5; i += 1024) {
    int row = i / 5, col = i - row * 5;
    float v = 0.f;
    if (col == 0) v = (float)b;
    else if (row < nAcc) {
      float4 bb = accB[row];
      v = (col == 1) ? bb.x : (col == 2) ? bb.y : (col == 3) ? bb.z : bb.w;
    }
    ob[i] = v;
  }
}

extern "C" void kernel_launch(void* const* d_in, const int* in_sizes, int n_in,
                              void* d_out, int out_size, void* d_ws, size_t ws_size,
                              hipStream_t stream) {
  const float* cls     = (const float*)d_in[0];
  const float* pred    = (const float*)d_in[1];
  const float* iminfo  = (const float*)d_in[2];
  const float* anchors = (const float*)d_in[3];
  float* out = (float*)d_out;
  u64* keys = (u64*)d_ws;   // 32*90000*8 = 23.04 MB

  int total = NB * NANCH;
  int blocks = (total + 255) / 256;
  k_decode<<<blocks, 256, 0, stream>>>(cls, pred, iminfo, anchors, keys);
  k_fused<<<NB, 1024, 0, stream>>>(keys, pred, iminfo, anchors, out);
}

// Round 9
// 347.973 us; speedup vs baseline: 2.0387x; 1.1131x over previous
//
#include <hip/hip_runtime.h>

#define NB 32
#define NA 9
#define FH 100
#define FW 100
#define HWSZ (FH*FW)          // 10000
#define NANCH (HWSZ*NA)       // 90000
#define PRE 6000
#define POST 300
#define SORTN 8192
#define NEGV -1000000000.0f
#define NMS_T 0.7f
#define MARG 1e-4f
#define NCHUNK ((PRE + 63) / 64)   // 94
#define SW(i) ((i) ^ (((i) >> 4) & 7))   // u64-LDS bank swizzle (bijective per 16-blk)
#define WB() __builtin_amdgcn_wave_barrier()

typedef unsigned long long u64;
typedef unsigned int u32;

__device__ __forceinline__ u32 f2sort(float f) {
  u32 u = __float_as_uint(f);
  return (u & 0x80000000u) ? ~u : (u | 0x80000000u);
}

__device__ __forceinline__ float4 decode_box(const float* __restrict__ pred,
                                             const float* __restrict__ anchors,
                                             int b, int i, float imw, float imh) {
  int hw = i / NA; int a = i - hw * NA;
  int h = hw / FW; int w = hw - h * FW;
  float sx = (float)(w * 16);
  float sy = (float)(h * 16);
  float ax1 = anchors[a*4+0] + sx, ay1 = anchors[a*4+1] + sy;
  float ax2 = anchors[a*4+2] + sx, ay2 = anchors[a*4+3] + sy;
  float wa = ax2 - ax1 + 1.0f, ha = ay2 - ay1 + 1.0f;
  float cxa = ax1 + 0.5f*(wa - 1.0f), cya = ay1 + 0.5f*(ha - 1.0f);
  size_t base = (((size_t)b*36 + a*4)*FH + h)*FW + w;
  float dx = pred[base];
  float dy = pred[base + HWSZ];
  float dw = pred[base + 2*HWSZ];
  float dh = pred[base + 3*HWSZ];
  float cx = dx*wa + cxa, cy = dy*ha + cya;
  float pw = expf(dw)*wa, ph = expf(dh)*ha;
  float x1 = fminf(fmaxf(cx - 0.5f*(pw - 1.0f), 0.0f), imw - 1.0f);
  float y1 = fminf(fmaxf(cy - 0.5f*(ph - 1.0f), 0.0f), imh - 1.0f);
  float x2 = fminf(fmaxf(cx + 0.5f*(pw - 1.0f), 0.0f), imw - 1.0f);
  float y2 = fminf(fmaxf(cy + 0.5f*(ph - 1.0f), 0.0f), imh - 1.0f);
  return make_float4(x1, y1, x2, y2);
}

// K1: per-anchor score with min-size filter -> sortable key
__global__ void k_decode(const float* __restrict__ cls,
                         const float* __restrict__ pred,
                         const float* __restrict__ iminfo,
                         const float* __restrict__ anchors,
                         u64* __restrict__ keys) {
  int gid = blockIdx.x * blockDim.x + threadIdx.x;
  if (gid >= NB * NANCH) return;
  int b = gid / NANCH;
  int i = gid - b * NANCH;
  int hw = i / NA; int a = i - hw * NA;
  int h = hw / FW; int w = hw - h * FW;
  float score = cls[(((size_t)b*18 + 9 + a)*FH + h)*FW + w];
  float imh = iminfo[b*3+0], imw = iminfo[b*3+1], sc = iminfo[b*3+2];
  float4 bx = decode_box(pred, anchors, b, i, imw, imh);
  float msz = 16.0f * sc;
  bool keep = ((bx.z - bx.x + 1.0f) >= msz) && ((bx.w - bx.y + 1.0f) >= msz);
  float sf = keep ? score : NEGV;
  u64 key = ((u64)f2sort(sf) << 32) | (u32)(~(u32)i);
  keys[(size_t)b * NANCH + i] = key;
}

// wave-0 suffix cut search over 4096-bin histogram.
__device__ __forceinline__ void w0_cut(unsigned int* hist, u32 target, int lane,
                                       int* cutBin, u32* nAfter) {
  u32 cs = 0;
  int cb = lane * 64;
  for (int i = 0; i < 64; ++i) cs += hist[cb + ((i + lane) & 63)];
  u32 suf = cs;
  #pragma unroll
  for (int d = 1; d < 64; d <<= 1) {
    u32 o = __shfl_down(suf, (unsigned)d, 64);
    suf += (lane < 64 - d) ? o : 0u;
  }
  u64 m1 = __ballot(suf >= target);
  int L = 63 - __clzll(m1);
  u32 nAb = (L < 63) ? (u32)__builtin_amdgcn_readlane((int)suf, L + 1) : 0u;
  u32 fs = hist[L * 64 + lane];
  #pragma unroll
  for (int d = 1; d < 64; d <<= 1) {
    u32 o = __shfl_down(fs, (unsigned)d, 64);
    fs += (lane < 64 - d) ? o : 0u;
  }
  fs += nAb;
  u64 m2 = __ballot(fs >= target);
  int fb = 63 - __clzll(m2);
  *cutBin = L * 64 + fb;
  *nAfter = (fb < 63) ? (u32)__builtin_amdgcn_readlane((int)fs, fb + 1) : nAb;
}

#define CEX(A,B,UP) { if ((UP) ? ((A) > (B)) : ((A) < (B))) { u64 _t=(A); (A)=(B); (B)=_t; } }

// LDS layout (bytes): cand u64[8192] @0; hist u32[4][4096] @65536;
// accB float4[300] @131072; accA f[300] @135872; aL f[36] @137072; scal @137216.
#define SMEM_BYTES 137280
__global__ __launch_bounds__(1024, 1) void k_fused(
    const u64* __restrict__ keys,
    const float* __restrict__ pred,
    const float* __restrict__ iminfo,
    const float* __restrict__ anchors,
    float* __restrict__ out) {
  __shared__ __align__(16) unsigned char smemRaw[SMEM_BYTES];
  u64* cand = (u64*)smemRaw;
  u32* hist = (u32*)(smemRaw + 65536);          // copy 0; copies at +4096*c
  float4* accB = (float4*)(smemRaw + 131072);
  float* accA = (float*)(smemRaw + 135872);
  float* aL = (float*)(smemRaw + 137072);
  int* scal = (int*)(smemRaw + 137216);

  const int b = blockIdx.x;
  const int tid = threadIdx.x;
  const int wave = tid >> 6, lane = tid & 63;
  const u64* kb = keys + (size_t)b * NANCH;
  const u32 liveThr = f2sort(-5.0e8f);
  u32* histW = hist + (wave & 3) * 4096;

  if (tid < 36) aL[tid] = anchors[tid];
  // ---- level-1 histogram (4-way replicated): sortable bits [31:20] ----
  for (int i = tid; i < 16384; i += 1024) hist[i] = 0;
  __syncthreads();
  for (int i = tid; i < NANCH; i += 1024)
    atomicAdd(&histW[(u32)(kb[i] >> 52)], 1u);
  __syncthreads();
  for (int i = tid; i < 4096; i += 1024)
    hist[i] = hist[i] + hist[i+4096] + hist[i+8192] + hist[i+12288];
  __syncthreads();
  if (wave == 0) {
    int cb; u32 nAf;
    w0_cut(hist, PRE, lane, &cb, &nAf);
    if (lane == 0) { scal[1] = cb; scal[2] = (int)nAf; }
  }
  __syncthreads();
  const int cb1 = scal[1];
  const u32 nG = (u32)scal[2];
  __syncthreads();

  // ---- level-2 histogram (replicated) within coarse bin: bits [19:8] ----
  for (int i = tid; i < 16384; i += 1024) hist[i] = 0;
  __syncthreads();
  for (int i = tid; i < NANCH; i += 1024) {
    u64 k = kb[i];
    if ((int)(k >> 52) == cb1)
      atomicAdd(&histW[(u32)((k >> 40) & 0xFFFull)], 1u);
  }
  __syncthreads();
  for (int i = tid; i < 4096; i += 1024)
    hist[i] = hist[i] + hist[i+4096] + hist[i+8192] + hist[i+12288];
  __syncthreads();
  if (wave == 0) {
    int cb2; u32 nAf2;
    w0_cut(hist, PRE - nG, lane, &cb2, &nAf2);
    if (lane == 0) scal[3] = cb2;
  }
  __syncthreads();
  const u32 thrT = ((u32)cb1 << 20) | ((u32)scal[3] << 8);

  // ---- compaction: wave-aggregated atomic; swizzled writes ----
  if (tid == 0) scal[0] = 0;
  __syncthreads();
  for (int i0 = 0; i0 < 90112; i0 += 1024) {
    int i = i0 + tid;
    u64 k = (i < NANCH) ? kb[i] : 0ull;
    bool pred_ = (i < NANCH) && ((u32)(k >> 32) >= thrT);
    u64 bal = __ballot(pred_);
    int cnt = __popcll(bal);
    int base = 0;
    if (lane == 0 && cnt) base = atomicAdd(&scal[0], cnt);
    base = __builtin_amdgcn_readfirstlane(base);
    int pos = base + __popcll(bal & ((1ull << lane) - 1ull));
    if (pred_ && pos < SORTN) cand[SW(pos)] = k;
  }
  __syncthreads();
  {
    int cnt = scal[0]; if (cnt > SORTN) cnt = SORTN;
    for (int i = tid; i < SORTN; i += 1024)
      if (i >= cnt) cand[SW(i)] = 0ull;
  }
  __syncthreads();

  // ---- bitonic sort (descending), swizzled LDS, wave-local when j<512 ----
  {
    int tb = tid * 8;
    u64 e0=cand[SW(tb+0)], e1=cand[SW(tb+1)], e2=cand[SW(tb+2)], e3=cand[SW(tb+3)];
    u64 e4=cand[SW(tb+4)], e5=cand[SW(tb+5)], e6=cand[SW(tb+6)], e7=cand[SW(tb+7)];
    bool u8b = (tb & 8) != 0;
    CEX(e0,e1,false) CEX(e2,e3,true) CEX(e4,e5,false) CEX(e6,e7,true)       // k=2
    CEX(e0,e2,false) CEX(e1,e3,false) CEX(e4,e6,true) CEX(e5,e7,true)       // k=4 j=2
    CEX(e0,e1,false) CEX(e2,e3,false) CEX(e4,e5,true) CEX(e6,e7,true)       // k=4 j=1
    CEX(e0,e4,u8b) CEX(e1,e5,u8b) CEX(e2,e6,u8b) CEX(e3,e7,u8b)             // k=8 j=4
    CEX(e0,e2,u8b) CEX(e1,e3,u8b) CEX(e4,e6,u8b) CEX(e5,e7,u8b)             // k=8 j=2
    CEX(e0,e1,u8b) CEX(e2,e3,u8b) CEX(e4,e5,u8b) CEX(e6,e7,u8b)             // k=8 j=1
    cand[SW(tb+0)]=e0; cand[SW(tb+1)]=e1; cand[SW(tb+2)]=e2; cand[SW(tb+3)]=e3;
    cand[SW(tb+4)]=e4; cand[SW(tb+5)]=e5; cand[SW(tb+6)]=e6; cand[SW(tb+7)]=e7;
    WB();
  }
  for (int k = 16; k <= SORTN; k <<= 1) {
    int j = k >> 1;
    for (; j >= 512; j >>= 1) {               // cross-wave steps (barriered)
      __syncthreads();
      for (int m = tid; m < SORTN/2; m += 1024) {
        int i = ((m & ~(j-1)) << 1) | (m & (j-1));
        int x = i | j;
        u64 a0 = cand[SW(i)], a1 = cand[SW(x)];
        bool up = (i & k) != 0;
        if (up ? (a0 > a1) : (a0 < a1)) { cand[SW(i)] = a1; cand[SW(x)] = a0; }
      }
    }
    if (k >= 1024) __syncthreads();           // transition to intra-wave
    for (; j >= 8; j >>= 1) {                 // intra-wave steps (no barrier)
      int base = wave * 512;
      for (int m = lane; m < 256; m += 64) {
        int lo = ((m & ~(j-1)) << 1) | (m & (j-1));
        int i = base + lo, x = i | j;
        u64 a0 = cand[SW(i)], a1 = cand[SW(x)];
        bool up = (i & k) != 0;
        if (up ? (a0 > a1) : (a0 < a1)) { cand[SW(i)] = a1; cand[SW(x)] = a0; }
      }
      WB();
    }
    {                                          // fused j=4,2,1 register tail
      int tb = tid * 8;
      u64 e0=cand[SW(tb+0)], e1=cand[SW(tb+1)], e2=cand[SW(tb+2)], e3=cand[SW(tb+3)];
      u64 e4=cand[SW(tb+4)], e5=cand[SW(tb+5)], e6=cand[SW(tb+6)], e7=cand[SW(tb+7)];
      bool up = (tb & k) != 0;
      CEX(e0,e4,up) CEX(e1,e5,up) CEX(e2,e6,up) CEX(e3,e7,up)
      CEX(e0,e2,up) CEX(e1,e3,up) CEX(e4,e6,up) CEX(e5,e7,up)
      CEX(e0,e1,up) CEX(e2,e3,up) CEX(e4,e5,up) CEX(e6,e7,up)
      cand[SW(tb+0)]=e0; cand[SW(tb+1)]=e1; cand[SW(tb+2)]=e2; cand[SW(tb+3)]=e3;
      cand[SW(tb+4)]=e4; cand[SW(tb+5)]=e5; cand[SW(tb+6)]=e6; cand[SW(tb+7)]=e7;
      WB();
    }
  }
  __syncthreads();

  // ---- NMS (wave 0): accepted-list, lazy decode, rcp fast-path IoU ----
  const float imh = iminfo[b*3+0], imw = iminfo[b*3+1];
  if (wave == 0) {
    int idxC; bool liveC; float dxC, dyC, dwC, dhC;
    {
      u64 k0 = cand[SW(lane)];
      liveC = ((u32)(k0 >> 32) > liveThr);
      idxC = (int)(~(u32)k0);
      bool v = (u32)idxC < (u32)NANCH;
      liveC = liveC && v;
      int id = v ? idxC : 0;
      int hw = id / NA; int a = id - hw * NA;
      int h = hw / FW; int w = hw - h * FW;
      size_t base = (((size_t)b*36 + a*4)*FH + h)*FW + w;
      dxC = pred[base]; dyC = pred[base + HWSZ];
      dwC = pred[base + 2*HWSZ]; dhC = pred[base + 3*HWSZ];
    }
    int nAcc = 0;
    for (int g = 0; g < NCHUNK && nAcc < POST; ++g) {
      float4 bc; float areaC; bool ok = liveC;
      {
        int id = ((u32)idxC < (u32)NANCH) ? idxC : 0;
        int hw = id / NA; int a = id - hw * NA;
        int h = hw / FW; int w = hw - h * FW;
        float sx = (float)(w * 16), sy = (float)(h * 16);
        float ax1 = aL[a*4+0] + sx, ay1 = aL[a*4+1] + sy;
        float ax2 = aL[a*4+2] + sx, ay2 = aL[a*4+3] + sy;
        float wa = ax2 - ax1 + 1.0f, ha = ay2 - ay1 + 1.0f;
        float cxa = ax1 + 0.5f*(wa - 1.0f), cya = ay1 + 0.5f*(ha - 1.0f);
        float cx = dxC*wa + cxa, cy = dyC*ha + cya;
        float pw = expf(dwC)*wa, ph = expf(dhC)*ha;
        bc.x = fminf(fmaxf(cx - 0.5f*(pw - 1.0f), 0.0f), imw - 1.0f);
        bc.y = fminf(fmaxf(cy - 0.5f*(ph - 1.0f), 0.0f), imh - 1.0f);
        bc.z = fminf(fmaxf(cx + 0.5f*(pw - 1.0f), 0.0f), imw - 1.0f);
        bc.w = fminf(fmaxf(cy + 0.5f*(ph - 1.0f), 0.0f), imh - 1.0f);
        areaC = (bc.z - bc.x + 1.0f) * (bc.w - bc.y + 1.0f);
      }
      // prefetch chunk g+1
      int idxN = 0; bool liveN = false;
      float dxN = 0.f, dyN = 0.f, dwN = 0.f, dhN = 0.f;
      if (g + 1 < NCHUNK) {
        int cn = (g + 1) * 64 + lane;
        u64 kn = cand[SW(cn)];
        liveN = ((u32)(kn >> 32) > liveThr) && (cn < PRE);
        idxN = (int)(~(u32)kn);
        bool v = (u32)idxN < (u32)NANCH;
        liveN = liveN && v;
        int id = v ? idxN : 0;
        int hw = id / NA; int a = id - hw * NA;
        int h = hw / FW; int w = hw - h * FW;
        size_t nb = (((size_t)b*36 + a*4)*FH + h)*FW + w;
        dxN = pred[nb]; dyN = pred[nb + HWSZ];
        dwN = pred[nb + 2*HWSZ]; dhN = pred[nb + 3*HWSZ];
      }
      // test vs accepted list (8-blocked, ballot early-out, rcp fast path)
      for (int t0 = 0; t0 < nAcc; t0 += 8) {
        if (__ballot(ok) == 0ull) break;
        int te = (t0 + 8 < nAcc) ? (t0 + 8) : nAcc;
        for (int tt = t0; tt < te; ++tt) {
          float4 ba = accB[tt];
          float aA = accA[tt];
          float xx1 = fmaxf(ba.x, bc.x);
          float yy1 = fmaxf(ba.y, bc.y);
          float xx2 = fminf(ba.z, bc.z);
          float yy2 = fminf(ba.w, bc.w);
          float inter = fmaxf(xx2 - xx1 + 1.0f, 0.0f) * fmaxf(yy2 - yy1 + 1.0f, 0.0f);
          float un = aA + areaC - inter;
          float q = inter * __builtin_amdgcn_rcpf(un);
          bool hi = q > NMS_T + MARG;
          bool lo = q < NMS_T - MARG;
          bool sup = hi;
          if (__ballot(ok && !hi && !lo)) {       // rare exact-div fallback
            if (!hi && !lo) sup = (inter / un) > NMS_T;
          }
          ok = ok && !sup;
        }
      }
      // in-chunk sequential resolution (exact division; ≤300 total)
      u64 bal = __ballot(ok);
      while (bal != 0ull && nAcc < POST) {
        int fl = __ffsll(bal) - 1;
        float ax1 = __int_as_float(__builtin_amdgcn_readlane(__float_as_int(bc.x), fl));
        float ay1 = __int_as_float(__builtin_amdgcn_readlane(__float_as_int(bc.y), fl));
        float ax2 = __int_as_float(__builtin_amdgcn_readlane(__float_as_int(bc.z), fl));
        float ay2 = __int_as_float(__builtin_amdgcn_readlane(__float_as_int(bc.w), fl));
        float aA = (ax2 - ax1 + 1.0f) * (ay2 - ay1 + 1.0f);
        if (lane == 0) { accB[nAcc] = make_float4(ax1, ay1, ax2, ay2); accA[nAcc] = aA; }
        ++nAcc;
        if (ok) {
          if (lane == fl) ok = false;
          else if (lane > fl) {
            float xx1 = fmaxf(ax1, bc.x);
            float yy1 = fmaxf(ay1, bc.y);
            float xx2 = fminf(ax2, bc.z);
            float yy2 = fminf(ay2, bc.w);
            float inter = fmaxf(xx2 - xx1 + 1.0f, 0.0f) * fmaxf(yy2 - yy1 + 1.0f, 0.0f);
            float iou = inter / (aA + areaC - inter);
            if (iou > NMS_T) ok = false;
          }
        }
        bal = __ballot(ok);
      }
      idxC = idxN; liveC = liveN;
      dxC = dxN; dyC = dyN; dwC = dwN; dhC = dhN;
    }
    if (lane == 0) scal[4] = nAcc;
  }
  __syncthreads();

  // ---- output: [b][POST][5] = (b, x1, y1, x2, y2); rows >= nAcc zeroed ----
  const int nAcc = scal[4];
  float* ob = out + (size_t)b * POST * 5;
  for (int i = tid; i < POST * 5; i += 1024) {
    int row = i / 5, col = i - row * 5;
    float v = 0.f;
    if (col == 0) v = (float)b;
    else if (row < nAcc) {
      float4 bb = accB[row];
      v = (col == 1) ? bb.x : (col == 2) ? bb.y : (col == 3) ? bb.z : bb.w;
    }
    ob[i] = v;
  }
}

extern "C" void kernel_launch(void* const* d_in, const int* in_sizes, int n_in,
                              void* d_out, int out_size, void* d_ws, size_t ws_size,
                              hipStream_t stream) {
  const float* cls     = (const float*)d_in[0];
  const float* pred    = (const float*)d_in[1];
  const float* iminfo  = (const float*)d_in[2];
  const float* anchors = (const float*)d_in[3];
  float* out = (float*)d_out;
  u64* keys = (u64*)d_ws;   // 32*90000*8 = 23.04 MB

  int total = NB * NANCH;
  int blocks = (total + 255) / 256;
  k_decode<<<blocks, 256, 0, stream>>>(cls, pred, iminfo, anchors, keys);
  k_fused<<<NB, 1024, 0, stream>>>(keys, pred, iminfo, anchors, out);
}

// Round 11
// 263.248 us; speedup vs baseline: 2.6949x; 1.3218x over previous
//
#include <hip/hip_runtime.h>

#define NB 32
#define NA 9
#define FH 100
#define FW 100
#define HWSZ (FH*FW)          // 10000
#define NANCH (HWSZ*NA)       // 90000
#define PRE 6000
#define POST 300
#define SORTN 8192
#define NEGV -1000000000.0f
#define NMS_T 0.7f
#define MARG 1e-4f
#define NCHUNK ((PRE + 63) / 64)   // 94
#define SW(i) ((i) ^ (((i) >> 4) & 7))   // u64-LDS bank swizzle
#define WB() __builtin_amdgcn_wave_barrier()
#define HSTRIDE 4104              // hist copy stride in u32 (+8 banks per copy)

typedef unsigned long long u64;
typedef unsigned int u32;

__device__ __forceinline__ u32 f2sort(float f) {
  u32 u = __float_as_uint(f);
  return (u & 0x80000000u) ? ~u : (u | 0x80000000u);
}

__device__ __forceinline__ float4 decode_box(const float* __restrict__ pred,
                                             const float* __restrict__ anchors,
                                             int b, int i, float imw, float imh) {
  int hw = i / NA; int a = i - hw * NA;
  int h = hw / FW; int w = hw - h * FW;
  float sx = (float)(w * 16);
  float sy = (float)(h * 16);
  float ax1 = anchors[a*4+0] + sx, ay1 = anchors[a*4+1] + sy;
  float ax2 = anchors[a*4+2] + sx, ay2 = anchors[a*4+3] + sy;
  float wa = ax2 - ax1 + 1.0f, ha = ay2 - ay1 + 1.0f;
  float cxa = ax1 + 0.5f*(wa - 1.0f), cya = ay1 + 0.5f*(ha - 1.0f);
  size_t base = (((size_t)b*36 + a*4)*FH + h)*FW + w;
  float dx = pred[base];
  float dy = pred[base + HWSZ];
  float dw = pred[base + 2*HWSZ];
  float dh = pred[base + 3*HWSZ];
  float cx = dx*wa + cxa, cy = dy*ha + cya;
  float pw = expf(dw)*wa, ph = expf(dh)*ha;
  float x1 = fminf(fmaxf(cx - 0.5f*(pw - 1.0f), 0.0f), imw - 1.0f);
  float y1 = fminf(fmaxf(cy - 0.5f*(ph - 1.0f), 0.0f), imh - 1.0f);
  float x2 = fminf(fmaxf(cx + 0.5f*(pw - 1.0f), 0.0f), imw - 1.0f);
  float y2 = fminf(fmaxf(cy + 0.5f*(ph - 1.0f), 0.0f), imh - 1.0f);
  return make_float4(x1, y1, x2, y2);
}

// K1: per-anchor score with min-size filter -> sortable u32 (index = position)
__global__ void k_decode(const float* __restrict__ cls,
                         const float* __restrict__ pred,
                         const float* __restrict__ iminfo,
                         const float* __restrict__ anchors,
                         u32* __restrict__ scoreg) {
  int gid = blockIdx.x * blockDim.x + threadIdx.x;
  if (gid >= NB * NANCH) return;
  int b = gid / NANCH;
  int i = gid - b * NANCH;
  int hw = i / NA; int a = i - hw * NA;
  int h = hw / FW; int w = hw - h * FW;
  float score = cls[(((size_t)b*18 + 9 + a)*FH + h)*FW + w];
  float imh = iminfo[b*3+0], imw = iminfo[b*3+1], sc = iminfo[b*3+2];
  float4 bx = decode_box(pred, anchors, b, i, imw, imh);
  float msz = 16.0f * sc;
  bool keep = ((bx.z - bx.x + 1.0f) >= msz) && ((bx.w - bx.y + 1.0f) >= msz);
  float sf = keep ? score : NEGV;
  scoreg[(size_t)b * NANCH + i] = f2sort(sf);
}

// wave-0 suffix cut search over merged 4096-bin histogram.
__device__ __forceinline__ void w0_cut(unsigned int* hist, u32 target, int lane,
                                       int* cutBin, u32* nAfter) {
  u32 cs = 0;
  int cb = lane * 64;
  for (int i = 0; i < 64; ++i) cs += hist[cb + ((i + lane) & 63)];
  u32 suf = cs;
  #pragma unroll
  for (int d = 1; d < 64; d <<= 1) {
    u32 o = __shfl_down(suf, (unsigned)d, 64);
    suf += (lane < 64 - d) ? o : 0u;
  }
  u64 m1 = __ballot(suf >= target);
  int L = 63 - __clzll(m1);
  u32 nAb = (L < 63) ? (u32)__builtin_amdgcn_readlane((int)suf, L + 1) : 0u;
  u32 fs = hist[L * 64 + lane];
  #pragma unroll
  for (int d = 1; d < 64; d <<= 1) {
    u32 o = __shfl_down(fs, (unsigned)d, 64);
    fs += (lane < 64 - d) ? o : 0u;
  }
  fs += nAb;
  u64 m2 = __ballot(fs >= target);
  int fb = 63 - __clzll(m2);
  *cutBin = L * 64 + fb;
  *nAfter = (fb < 63) ? (u32)__builtin_amdgcn_readlane((int)fs, fb + 1) : nAb;
}

#define CEX(A,B,UP) { if ((UP) ? ((A) > (B)) : ((A) < (B))) { u64 _t=(A); (A)=(B); (B)=_t; } }

// LDS (bytes): cand u64[8192] @0 (65536); hist u32[4*4104] @65536 (65664, ends 131200);
// scal @131200 (64); aL @131264 (144) -> SMEM 131408.
// NMS overlay (cand+hist dead): boxes float4[6016] @0 (96256);
// liveM u64[96] @96256 (768); accB float4[300] @97024 (4800);
// accA f[300] @101824 (1200); okm u64[16] @103040 (128).
#define SMEM_BYTES 131408
__global__ __launch_bounds__(1024, 1) void k_fused(
    const u32* __restrict__ scoreg,
    const float* __restrict__ pred,
    const float* __restrict__ iminfo,
    const float* __restrict__ anchors,
    float* __restrict__ out) {
  __shared__ __align__(16) unsigned char smemRaw[SMEM_BYTES];
  u64* cand = (u64*)smemRaw;
  u32* hist = (u32*)(smemRaw + 65536);
  int* scal = (int*)(smemRaw + 131200);
  float* aL = (float*)(smemRaw + 131264);
  float4* boxes = (float4*)smemRaw;
  u64* liveM = (u64*)(smemRaw + 96256);
  float4* accB = (float4*)(smemRaw + 97024);
  float* accA = (float*)(smemRaw + 101824);
  u64* okm = (u64*)(smemRaw + 103040);

  const int b = blockIdx.x;
  const int tid = threadIdx.x;
  const int wave = tid >> 6, lane = tid & 63;
  const u32* sb = scoreg + (size_t)b * NANCH;
  const u32 liveThr = f2sort(-5.0e8f);
  u32* histW = hist + (lane & 3) * HSTRIDE;     // copy by LANE -> spread hot bins

  if (tid < 36) aL[tid] = anchors[tid];
  // ---- level-1 histogram: sortable bits [31:20] ----
  for (int i = tid; i < 4*HSTRIDE; i += 1024) hist[i] = 0;
  __syncthreads();
  for (int i = tid; i < NANCH; i += 1024)
    atomicAdd(&histW[sb[i] >> 20], 1u);
  __syncthreads();
  for (int i = tid; i < 4096; i += 1024)
    hist[i] = hist[i] + hist[i+HSTRIDE] + hist[i+2*HSTRIDE] + hist[i+3*HSTRIDE];
  __syncthreads();
  if (wave == 0) {
    int cb; u32 nAf;
    w0_cut(hist, PRE, lane, &cb, &nAf);
    if (lane == 0) { scal[1] = cb; scal[2] = (int)nAf; }
  }
  __syncthreads();
  const int cb1 = scal[1];
  const u32 nG = (u32)scal[2];
  __syncthreads();

  // ---- level-2 histogram within coarse bin: bits [19:8] ----
  for (int i = tid; i < 4*HSTRIDE; i += 1024) hist[i] = 0;
  __syncthreads();
  for (int i = tid; i < NANCH; i += 1024) {
    u32 s = sb[i];
    if ((int)(s >> 20) == cb1)
      atomicAdd(&histW[(s >> 8) & 0xFFFu], 1u);
  }
  __syncthreads();
  for (int i = tid; i < 4096; i += 1024)
    hist[i] = hist[i] + hist[i+HSTRIDE] + hist[i+2*HSTRIDE] + hist[i+3*HSTRIDE];
  __syncthreads();
  if (wave == 0) {
    int cb2; u32 nAf2;
    w0_cut(hist, PRE - nG, lane, &cb2, &nAf2);
    if (lane == 0) scal[3] = cb2;
  }
  __syncthreads();
  const u32 thrT = ((u32)cb1 << 20) | ((u32)scal[3] << 8);

  // ---- compaction: wave-aggregated atomic; key rebuilt from (s, pos) ----
  if (tid == 0) scal[0] = 0;
  __syncthreads();
  for (int i0 = 0; i0 < 90112; i0 += 1024) {
    int i = i0 + tid;
    u32 s = (i < NANCH) ? sb[i] : 0u;
    bool pred_ = (i < NANCH) && (s >= thrT);
    u64 bal = __ballot(pred_);
    int cnt = __popcll(bal);
    int base = 0;
    if (lane == 0 && cnt) base = atomicAdd(&scal[0], cnt);
    base = __builtin_amdgcn_readfirstlane(base);
    int pos = base + __popcll(bal & ((1ull << lane) - 1ull));
    if (pred_ && pos < SORTN) cand[SW(pos)] = ((u64)s << 32) | (u32)(~(u32)i);
  }
  __syncthreads();
  {
    int cnt = scal[0]; if (cnt > SORTN) cnt = SORTN;
    for (int i = tid; i < SORTN; i += 1024)
      if (i >= cnt) cand[SW(i)] = 0ull;
  }
  __syncthreads();

  // ---- bitonic sort (descending), swizzled LDS, wave-local when j<512 ----
  {
    int tb = tid * 8;
    u64 e0=cand[SW(tb+0)], e1=cand[SW(tb+1)], e2=cand[SW(tb+2)], e3=cand[SW(tb+3)];
    u64 e4=cand[SW(tb+4)], e5=cand[SW(tb+5)], e6=cand[SW(tb+6)], e7=cand[SW(tb+7)];
    bool u8b = (tb & 8) != 0;
    CEX(e0,e1,false) CEX(e2,e3,true) CEX(e4,e5,false) CEX(e6,e7,true)
    CEX(e0,e2,false) CEX(e1,e3,false) CEX(e4,e6,true) CEX(e5,e7,true)
    CEX(e0,e1,false) CEX(e2,e3,false) CEX(e4,e5,true) CEX(e6,e7,true)
    CEX(e0,e4,u8b) CEX(e1,e5,u8b) CEX(e2,e6,u8b) CEX(e3,e7,u8b)
    CEX(e0,e2,u8b) CEX(e1,e3,u8b) CEX(e4,e6,u8b) CEX(e5,e7,u8b)
    CEX(e0,e1,u8b) CEX(e2,e3,u8b) CEX(e4,e5,u8b) CEX(e6,e7,u8b)
    cand[SW(tb+0)]=e0; cand[SW(tb+1)]=e1; cand[SW(tb+2)]=e2; cand[SW(tb+3)]=e3;
    cand[SW(tb+4)]=e4; cand[SW(tb+5)]=e5; cand[SW(tb+6)]=e6; cand[SW(tb+7)]=e7;
    WB();
  }
  for (int k = 16; k <= SORTN; k <<= 1) {
    int j = k >> 1;
    for (; j >= 512; j >>= 1) {
      __syncthreads();
      for (int m = tid; m < SORTN/2; m += 1024) {
        int i = ((m & ~(j-1)) << 1) | (m & (j-1));
        int x = i | j;
        u64 a0 = cand[SW(i)], a1 = cand[SW(x)];
        bool up = (i & k) != 0;
        if (up ? (a0 > a1) : (a0 < a1)) { cand[SW(i)] = a1; cand[SW(x)] = a0; }
      }
    }
    if (k >= 1024) __syncthreads();
    for (; j >= 8; j >>= 1) {
      int base = wave * 512;
      for (int m = lane; m < 256; m += 64) {
        int lo = ((m & ~(j-1)) << 1) | (m & (j-1));
        int i = base + lo, x = i | j;
        u64 a0 = cand[SW(i)], a1 = cand[SW(x)];
        bool up = (i & k) != 0;
        if (up ? (a0 > a1) : (a0 < a1)) { cand[SW(i)] = a1; cand[SW(x)] = a0; }
      }
      WB();
    }
    {
      int tb = tid * 8;
      u64 e0=cand[SW(tb+0)], e1=cand[SW(tb+1)], e2=cand[SW(tb+2)], e3=cand[SW(tb+3)];
      u64 e4=cand[SW(tb+4)], e5=cand[SW(tb+5)], e6=cand[SW(tb+6)], e7=cand[SW(tb+7)];
      bool up = (tb & k) != 0;
      CEX(e0,e4,up) CEX(e1,e5,up) CEX(e2,e6,up) CEX(e3,e7,up)
      CEX(e0,e2,up) CEX(e1,e3,up) CEX(e4,e6,up) CEX(e5,e7,up)
      CEX(e0,e1,up) CEX(e2,e3,up) CEX(e4,e5,up) CEX(e6,e7,up)
      cand[SW(tb+0)]=e0; cand[SW(tb+1)]=e1; cand[SW(tb+2)]=e2; cand[SW(tb+3)]=e3;
      cand[SW(tb+4)]=e4; cand[SW(tb+5)]=e5; cand[SW(tb+6)]=e6; cand[SW(tb+7)]=e7;
      WB();
    }
  }
  __syncthreads();

  // ---- NMS Phase A: stage sorted entries -> decode ALL boxes into LDS ----
  const float imh = iminfo[b*3+0], imw = iminfo[b*3+1];
  u64 ce[6];
  #pragma unroll
  for (int r = 0; r < 6; ++r) {
    int i = tid + 1024 * r;                 // chunk = wave + 16r
    ce[r] = (i < NCHUNK*64) ? cand[SW(i)] : 0ull;
  }
  __syncthreads();                           // cand reads done; overlay begins
  #pragma unroll
  for (int r = 0; r < 6; ++r) {
    int c = wave + 16 * r;                   // wave-uniform chunk id
    if (c < NCHUNK) {
      int i = tid + 1024 * r;
      u64 k = ce[r];
      int idx = (int)(~(u32)k);
      bool v = (u32)idx < (u32)NANCH;
      bool live = ((u32)(k >> 32) > liveThr) && v && (i < PRE);
      int id = v ? idx : 0;
      int hw = id / NA; int a = id - hw * NA;
      int h = hw / FW; int w = hw - h * FW;
      float sx = (float)(w * 16), sy = (float)(h * 16);
      float ax1 = aL[a*4+0] + sx, ay1 = aL[a*4+1] + sy;
      float ax2 = aL[a*4+2] + sx, ay2 = aL[a*4+3] + sy;
      float wa = ax2 - ax1 + 1.0f, ha = ay2 - ay1 + 1.0f;
      float cxa = ax1 + 0.5f*(wa - 1.0f), cya = ay1 + 0.5f*(ha - 1.0f);
      size_t base = (((size_t)b*36 + a*4)*FH + h)*FW + w;
      float dx = pred[base], dy = pred[base + HWSZ];
      float dw = pred[base + 2*HWSZ], dh = pred[base + 3*HWSZ];
      float cx = dx*wa + cxa, cy = dy*ha + cya;
      float pw = expf(dw)*wa, ph = expf(dh)*ha;
      float4 bc;
      bc.x = fminf(fmaxf(cx - 0.5f*(pw - 1.0f), 0.0f), imw - 1.0f);
      bc.y = fminf(fmaxf(cy - 0.5f*(ph - 1.0f), 0.0f), imh - 1.0f);
      bc.z = fminf(fmaxf(cx + 0.5f*(pw - 1.0f), 0.0f), imw - 1.0f);
      bc.w = fminf(fmaxf(cy + 0.5f*(ph - 1.0f), 0.0f), imh - 1.0f);
      boxes[i] = bc;
      u64 lm = __ballot(live);
      if (lane == 0) liveM[c] = lm;
    }
  }
  if (tid == 0) scal[4] = 0;
  __syncthreads();

  // ---- NMS Phase B: per chunk, 16-wave-parallel accepted-list testing ----
  for (int g = 0; g < NCHUNK; ++g) {
    int nA = scal[4];
    if (nA >= POST) break;                   // uniform
    u64 lm = liveM[g];
    if (lm == 0ull) continue;                // uniform skip (no barriers taken)
    float4 bc = boxes[g * 64 + lane];
    float areaC = (bc.z - bc.x + 1.0f) * (bc.w - bc.y + 1.0f);
    bool ok = (lm >> lane) & 1ull;
    for (int tt = wave; tt < nA; tt += 16) {
      if (__ballot(ok) == 0ull) break;
      float4 ba = accB[tt];
      float aA = accA[tt];
      float xx1 = fmaxf(ba.x, bc.x);
      float yy1 = fmaxf(ba.y, bc.y);
      float xx2 = fminf(ba.z, bc.z);
      float yy2 = fminf(ba.w, bc.w);
      float inter = fmaxf(xx2 - xx1 + 1.0f, 0.0f) * fmaxf(yy2 - yy1 + 1.0f, 0.0f);
      float un = aA + areaC - inter;
      float q = inter * __builtin_amdgcn_rcpf(un);
      bool hi = q > NMS_T + MARG;
      bool lo = q < NMS_T - MARG;
      bool sup = hi;
      if (__ballot(ok && !hi && !lo)) {
        if (!hi && !lo) sup = (inter / un) > NMS_T;
      }
      ok = ok && !sup;
    }
    u64 wm = __ballot(ok);                   // FULL-EXEC ballot (R10 bug fix)
    if (lane == 0) okm[wave] = wm;
    __syncthreads();
    if (wave == 0) {
      u64 m = okm[0];
      #pragma unroll
      for (int w = 1; w < 16; ++w) m &= okm[w];
      bool ok0 = (m >> lane) & 1ull;
      int nAcc = nA;
      u64 bal = __ballot(ok0);
      while (bal != 0ull && nAcc < POST) {
        int fl = __ffsll(bal) - 1;
        float ax1 = __int_as_float(__builtin_amdgcn_readlane(__float_as_int(bc.x), fl));
        float ay1 = __int_as_float(__builtin_amdgcn_readlane(__float_as_int(bc.y), fl));
        float ax2 = __int_as_float(__builtin_amdgcn_readlane(__float_as_int(bc.z), fl));
        float ay2 = __int_as_float(__builtin_amdgcn_readlane(__float_as_int(bc.w), fl));
        float aA = (ax2 - ax1 + 1.0f) * (ay2 - ay1 + 1.0f);
        if (lane == 0) { accB[nAcc] = make_float4(ax1, ay1, ax2, ay2); accA[nAcc] = aA; }
        ++nAcc;
        if (ok0) {
          if (lane == fl) ok0 = false;
          else if (lane > fl) {
            float xx1 = fmaxf(ax1, bc.x);
            float yy1 = fmaxf(ay1, bc.y);
            float xx2 = fminf(ax2, bc.z);
            float yy2 = fminf(ay2, bc.w);
            float inter = fmaxf(xx2 - xx1 + 1.0f, 0.0f) * fmaxf(yy2 - yy1 + 1.0f, 0.0f);
            float iou = inter / (aA + areaC - inter);
            if (iou > NMS_T) ok0 = false;
          }
        }
        bal = __ballot(ok0);
      }
      if (lane == 0) scal[4] = nAcc;
    }
    __syncthreads();
  }

  // ---- output: [b][POST][5] = (b, x1, y1, x2, y2); rows >= nAcc zeroed ----
  const int nAcc = scal[4];
  float* ob = out + (size_t)b * POST * 5;
  for (int i = tid; i < POST * 5; i += 1024) {
    int row = i / 5, col = i - row * 5;
    float v = 0.f;
    if (col == 0) v = (float)b;
    else if (row < nAcc) {
      float4 bb = accB[row];
      v = (col == 1) ? bb.x : (col == 2) ? bb.y : (col == 3) ? bb.z : bb.w;
    }
    ob[i] = v;
  }
}

extern "C" void kernel_launch(void* const* d_in, const int* in_sizes, int n_in,
                              void* d_out, int out_size, void* d_ws, size_t ws_size,
                              hipStream_t stream) {
  const float* cls     = (const float*)d_in[0];
  const float* pred    = (const float*)d_in[1];
  const float* iminfo  = (const float*)d_in[2];
  const float* anchors = (const float*)d_in[3];
  float* out = (float*)d_out;
  u32* scoreg = (u32*)d_ws;   // 32*90000*4 = 11.52 MB

  int total = NB * NANCH;
  int blocks = (total + 255) / 256;
  k_decode<<<blocks, 256, 0, stream>>>(cls, pred, iminfo, anchors, scoreg);
  k_fused<<<NB, 1024, 0, stream>>>(scoreg, pred, iminfo, anchors, out);
}

// Round 12
// 238.832 us; speedup vs baseline: 2.9704x; 1.1022x over previous
//
#include <hip/hip_runtime.h>

#define NB 32
#define NA 9
#define FH 100
#define FW 100
#define HWSZ (FH*FW)          // 10000
#define NANCH (HWSZ*NA)       // 90000
#define PRE 6000
#define POST 300
#define SORTN 8192
#define NEGV -1000000000.0f
#define NMS_T 0.7f
#define MARG 1e-4f
#define NCHUNK ((PRE + 63) / 64)   // 94
#define SW(i) ((i) ^ (((i) >> 4) & 7))   // u64-LDS bank swizzle
#define WB() __builtin_amdgcn_wave_barrier()
#define NSLICE 11                 // k_decode slices per batch: 11*8192 >= 90000
#define DSLICE 8192

typedef unsigned long long u64;
typedef unsigned int u32;

__device__ __forceinline__ u32 f2sort(float f) {
  u32 u = __float_as_uint(f);
  return (u & 0x80000000u) ? ~u : (u | 0x80000000u);
}

__device__ __forceinline__ float4 decode_box(const float* __restrict__ pred,
                                             const float* __restrict__ anchors,
                                             int b, int i, float imw, float imh) {
  int hw = i / NA; int a = i - hw * NA;
  int h = hw / FW; int w = hw - h * FW;
  float sx = (float)(w * 16);
  float sy = (float)(h * 16);
  float ax1 = anchors[a*4+0] + sx, ay1 = anchors[a*4+1] + sy;
  float ax2 = anchors[a*4+2] + sx, ay2 = anchors[a*4+3] + sy;
  float wa = ax2 - ax1 + 1.0f, ha = ay2 - ay1 + 1.0f;
  float cxa = ax1 + 0.5f*(wa - 1.0f), cya = ay1 + 0.5f*(ha - 1.0f);
  size_t base = (((size_t)b*36 + a*4)*FH + h)*FW + w;
  float dx = pred[base];
  float dy = pred[base + HWSZ];
  float dw = pred[base + 2*HWSZ];
  float dh = pred[base + 3*HWSZ];
  float cx = dx*wa + cxa, cy = dy*ha + cya;
  float pw = expf(dw)*wa, ph = expf(dh)*ha;
  float x1 = fminf(fmaxf(cx - 0.5f*(pw - 1.0f), 0.0f), imw - 1.0f);
  float y1 = fminf(fmaxf(cy - 0.5f*(ph - 1.0f), 0.0f), imh - 1.0f);
  float x2 = fminf(fmaxf(cx + 0.5f*(pw - 1.0f), 0.0f), imw - 1.0f);
  float y2 = fminf(fmaxf(cy + 0.5f*(ph - 1.0f), 0.0f), imh - 1.0f);
  return make_float4(x1, y1, x2, y2);
}

// K0: zero the per-batch global histograms
__global__ void k_zero(u32* __restrict__ histg) {
  int i = blockIdx.x * 1024 + threadIdx.x;
  if (i < NB * 4096) histg[i] = 0;
}

// K1: per-anchor score + min-size filter -> sortable u32; fused LINEAR hist
// (bin = trunc(score*4096): uniform scores -> flat bins, no hot atomics)
__global__ __launch_bounds__(1024) void k_decode(
    const float* __restrict__ cls,
    const float* __restrict__ pred,
    const float* __restrict__ iminfo,
    const float* __restrict__ anchors,
    u32* __restrict__ scoreg,
    u32* __restrict__ histg) {
  __shared__ u32 hl[4096];
  const int blk = blockIdx.x;
  const int b = blk / NSLICE, s = blk - b * NSLICE;
  const int tid = threadIdx.x;
  for (int j = tid; j < 4096; j += 1024) hl[j] = 0;
  __syncthreads();
  const float imh = iminfo[b*3+0], imw = iminfo[b*3+1], sc = iminfo[b*3+2];
  const float msz = 16.0f * sc;
  #pragma unroll
  for (int r = 0; r < 8; ++r) {
    int i = s * DSLICE + r * 1024 + tid;
    if (i < NANCH) {
      int hw = i / NA; int a = i - hw * NA;
      int h = hw / FW; int w = hw - h * FW;
      float score = cls[(((size_t)b*18 + 9 + a)*FH + h)*FW + w];
      float4 bx = decode_box(pred, anchors, b, i, imw, imh);
      bool keep = ((bx.z - bx.x + 1.0f) >= msz) && ((bx.w - bx.y + 1.0f) >= msz);
      float sf = keep ? score : NEGV;
      float t = sf * 4096.0f;
      int bin = (t <= 0.0f) ? 0 : ((t >= 4095.0f) ? 4095 : (int)t);
      atomicAdd(&hl[bin], 1u);
      scoreg[(size_t)b * NANCH + i] = f2sort(sf);
    }
  }
  __syncthreads();
  for (int j = tid; j < 4096; j += 1024) {
    u32 v = hl[j];
    if (v) atomicAdd(&histg[b * 4096 + j], v);
  }
}

// wave-0 suffix cut search over 4096-bin histogram.
__device__ __forceinline__ void w0_cut(u32* hist, u32 target, int lane,
                                       int* cutBin) {
  u32 cs = 0;
  int cb = lane * 64;
  for (int i = 0; i < 64; ++i) cs += hist[cb + ((i + lane) & 63)];
  u32 suf = cs;
  #pragma unroll
  for (int d = 1; d < 64; d <<= 1) {
    u32 o = __shfl_down(suf, (unsigned)d, 64);
    suf += (lane < 64 - d) ? o : 0u;
  }
  u64 m1 = __ballot(suf >= target);
  int L = 63 - __clzll(m1);
  u32 nAb = (L < 63) ? (u32)__builtin_amdgcn_readlane((int)suf, L + 1) : 0u;
  u32 fs = hist[L * 64 + lane];
  #pragma unroll
  for (int d = 1; d < 64; d <<= 1) {
    u32 o = __shfl_down(fs, (unsigned)d, 64);
    fs += (lane < 64 - d) ? o : 0u;
  }
  fs += nAb;
  u64 m2 = __ballot(fs >= target);
  int fb = 63 - __clzll(m2);
  *cutBin = L * 64 + fb;
}

#define CEX(A,B,UP) { if ((UP) ? ((A) > (B)) : ((A) < (B))) { u64 _t=(A); (A)=(B); (B)=_t; } }

// LDS (bytes): cand u64[8192] @0 (65536); histL u32[4096] @65536..81920.
// NMS overlay (cand+histL dead): boxes float4[6016] @0..96256;
// liveM u64[96] @96256..97024; accB float4[300] @97024..101824;
// accA f[300] @101824..103024; okm u64[16] @103040..103168.
// Non-overlaid: scal @103168 (64); aL @103232 (144).
#define SMEM_BYTES 103424
__global__ __launch_bounds__(1024, 1) void k_fused(
    const u32* __restrict__ scoreg,
    const u32* __restrict__ histg,
    const float* __restrict__ pred,
    const float* __restrict__ iminfo,
    const float* __restrict__ anchors,
    float* __restrict__ out) {
  __shared__ __align__(16) unsigned char smemRaw[SMEM_BYTES];
  u64* cand = (u64*)smemRaw;
  u32* histL = (u32*)(smemRaw + 65536);
  float4* boxes = (float4*)smemRaw;
  u64* liveM = (u64*)(smemRaw + 96256);
  float4* accB = (float4*)(smemRaw + 97024);
  float* accA = (float*)(smemRaw + 101824);
  u64* okm = (u64*)(smemRaw + 103040);
  int* scal = (int*)(smemRaw + 103168);
  float* aL = (float*)(smemRaw + 103232);

  const int b = blockIdx.x;
  const int tid = threadIdx.x;
  const int wave = tid >> 6, lane = tid & 63;
  const u32* sb = scoreg + (size_t)b * NANCH;
  const u32 liveThr = f2sort(-5.0e8f);

  if (tid < 36) aL[tid] = anchors[tid];
  // ---- load per-batch hist; wave-0 cut ----
  for (int j = tid; j < 4096; j += 1024) histL[j] = histg[b * 4096 + j];
  if (tid == 0) scal[0] = 0;
  __syncthreads();
  if (wave == 0) {
    int L;
    w0_cut(histL, PRE, lane, &L);
    if (lane == 0) scal[1] = L;
  }
  __syncthreads();
  const u32 thrT = f2sort((float)scal[1] * (1.0f / 4096.0f));

  // ---- compaction: uint4 loads + wave-aggregated atomic ----
  const uint4* sb4 = (const uint4*)sb;          // 22500 uint4 = 90000 u32
  for (int t = 0; t < 22; ++t) {
    int vi = t * 1024 + tid;
    bool inb = vi < 22500;
    uint4 v = inb ? sb4[vi] : make_uint4(0, 0, 0, 0);
    int i0 = vi * 4;
    #pragma unroll
    for (int c = 0; c < 4; ++c) {
      u32 s = (&v.x)[c];
      bool p = inb && (s >= thrT);
      u64 bal = __ballot(p);
      int cnt = __popcll(bal);
      int base = 0;
      if (lane == 0 && cnt) base = atomicAdd(&scal[0], cnt);
      base = __builtin_amdgcn_readfirstlane(base);
      int pos = base + __popcll(bal & ((1ull << lane) - 1ull));
      if (p && pos < SORTN) cand[SW(pos)] = ((u64)s << 32) | (u32)(~(u32)(i0 + c));
    }
  }
  __syncthreads();
  {
    int cnt = scal[0]; if (cnt > SORTN) cnt = SORTN;
    for (int i = tid; i < SORTN; i += 1024)
      if (i >= cnt) cand[SW(i)] = 0ull;
  }
  __syncthreads();

  // ---- bitonic sort (descending), swizzled LDS, wave-local when j<512 ----
  {
    int tb = tid * 8;
    u64 e0=cand[SW(tb+0)], e1=cand[SW(tb+1)], e2=cand[SW(tb+2)], e3=cand[SW(tb+3)];
    u64 e4=cand[SW(tb+4)], e5=cand[SW(tb+5)], e6=cand[SW(tb+6)], e7=cand[SW(tb+7)];
    bool u8b = (tb & 8) != 0;
    CEX(e0,e1,false) CEX(e2,e3,true) CEX(e4,e5,false) CEX(e6,e7,true)
    CEX(e0,e2,false) CEX(e1,e3,false) CEX(e4,e6,true) CEX(e5,e7,true)
    CEX(e0,e1,false) CEX(e2,e3,false) CEX(e4,e5,true) CEX(e6,e7,true)
    CEX(e0,e4,u8b) CEX(e1,e5,u8b) CEX(e2,e6,u8b) CEX(e3,e7,u8b)
    CEX(e0,e2,u8b) CEX(e1,e3,u8b) CEX(e4,e6,u8b) CEX(e5,e7,u8b)
    CEX(e0,e1,u8b) CEX(e2,e3,u8b) CEX(e4,e5,u8b) CEX(e6,e7,u8b)
    cand[SW(tb+0)]=e0; cand[SW(tb+1)]=e1; cand[SW(tb+2)]=e2; cand[SW(tb+3)]=e3;
    cand[SW(tb+4)]=e4; cand[SW(tb+5)]=e5; cand[SW(tb+6)]=e6; cand[SW(tb+7)]=e7;
    WB();
  }
  for (int k = 16; k <= SORTN; k <<= 1) {
    int j = k >> 1;
    for (; j >= 512; j >>= 1) {
      __syncthreads();
      for (int m = tid; m < SORTN/2; m += 1024) {
        int i = ((m & ~(j-1)) << 1) | (m & (j-1));
        int x = i | j;
        u64 a0 = cand[SW(i)], a1 = cand[SW(x)];
        bool up = (i & k) != 0;
        if (up ? (a0 > a1) : (a0 < a1)) { cand[SW(i)] = a1; cand[SW(x)] = a0; }
      }
    }
    if (k >= 1024) __syncthreads();
    for (; j >= 8; j >>= 1) {
      int base = wave * 512;
      for (int m = lane; m < 256; m += 64) {
        int lo = ((m & ~(j-1)) << 1) | (m & (j-1));
        int i = base + lo, x = i | j;
        u64 a0 = cand[SW(i)], a1 = cand[SW(x)];
        bool up = (i & k) != 0;
        if (up ? (a0 > a1) : (a0 < a1)) { cand[SW(i)] = a1; cand[SW(x)] = a0; }
      }
      WB();
    }
    {
      int tb = tid * 8;
      u64 e0=cand[SW(tb+0)], e1=cand[SW(tb+1)], e2=cand[SW(tb+2)], e3=cand[SW(tb+3)];
      u64 e4=cand[SW(tb+4)], e5=cand[SW(tb+5)], e6=cand[SW(tb+6)], e7=cand[SW(tb+7)];
      bool up = (tb & k) != 0;
      CEX(e0,e4,up) CEX(e1,e5,up) CEX(e2,e6,up) CEX(e3,e7,up)
      CEX(e0,e2,up) CEX(e1,e3,up) CEX(e4,e6,up) CEX(e5,e7,up)
      CEX(e0,e1,up) CEX(e2,e3,up) CEX(e4,e5,up) CEX(e6,e7,up)
      cand[SW(tb+0)]=e0; cand[SW(tb+1)]=e1; cand[SW(tb+2)]=e2; cand[SW(tb+3)]=e3;
      cand[SW(tb+4)]=e4; cand[SW(tb+5)]=e5; cand[SW(tb+6)]=e6; cand[SW(tb+7)]=e7;
      WB();
    }
  }
  __syncthreads();

  // ---- NMS Phase A: stage sorted entries -> decode ALL boxes into LDS ----
  const float imh = iminfo[b*3+0], imw = iminfo[b*3+1];
  u64 ce[6];
  #pragma unroll
  for (int r = 0; r < 6; ++r) {
    int i = tid + 1024 * r;                 // chunk = wave + 16r
    ce[r] = (i < NCHUNK*64) ? cand[SW(i)] : 0ull;
  }
  __syncthreads();                           // cand reads done; overlay begins
  #pragma unroll
  for (int r = 0; r < 6; ++r) {
    int c = wave + 16 * r;                   // wave-uniform chunk id
    if (c < NCHUNK) {
      int i = tid + 1024 * r;
      u64 k = ce[r];
      int idx = (int)(~(u32)k);
      bool v = (u32)idx < (u32)NANCH;
      bool live = ((u32)(k >> 32) > liveThr) && v && (i < PRE);
      int id = v ? idx : 0;
      int hw = id / NA; int a = id - hw * NA;
      int h = hw / FW; int w = hw - h * FW;
      float sx = (float)(w * 16), sy = (float)(h * 16);
      float ax1 = aL[a*4+0] + sx, ay1 = aL[a*4+1] + sy;
      float ax2 = aL[a*4+2] + sx, ay2 = aL[a*4+3] + sy;
      float wa = ax2 - ax1 + 1.0f, ha = ay2 - ay1 + 1.0f;
      float cxa = ax1 + 0.5f*(wa - 1.0f), cya = ay1 + 0.5f*(ha - 1.0f);
      size_t base = (((size_t)b*36 + a*4)*FH + h)*FW + w;
      float dx = pred[base], dy = pred[base + HWSZ];
      float dw = pred[base + 2*HWSZ], dh = pred[base + 3*HWSZ];
      float cx = dx*wa + cxa, cy = dy*ha + cya;
      float pw = expf(dw)*wa, ph = expf(dh)*ha;
      float4 bc;
      bc.x = fminf(fmaxf(cx - 0.5f*(pw - 1.0f), 0.0f), imw - 1.0f);
      bc.y = fminf(fmaxf(cy - 0.5f*(ph - 1.0f), 0.0f), imh - 1.0f);
      bc.z = fminf(fmaxf(cx + 0.5f*(pw - 1.0f), 0.0f), imw - 1.0f);
      bc.w = fminf(fmaxf(cy + 0.5f*(ph - 1.0f), 0.0f), imh - 1.0f);
      boxes[i] = bc;
      u64 lm = __ballot(live);
      if (lane == 0) liveM[c] = lm;
    }
  }
  if (tid == 0) scal[4] = 0;
  __syncthreads();

  // ---- NMS Phase B: per chunk, 16-wave-parallel accepted-list testing ----
  for (int g = 0; g < NCHUNK; ++g) {
    int nA = scal[4];
    if (nA >= POST) break;                   // uniform
    u64 lm = liveM[g];
    if (lm == 0ull) continue;                // uniform skip
    float4 bc = boxes[g * 64 + lane];
    float areaC = (bc.z - bc.x + 1.0f) * (bc.w - bc.y + 1.0f);
    bool ok = (lm >> lane) & 1ull;
    for (int tt = wave; tt < nA; tt += 16) {
      if (__ballot(ok) == 0ull) break;
      float4 ba = accB[tt];
      float aA = accA[tt];
      float xx1 = fmaxf(ba.x, bc.x);
      float yy1 = fmaxf(ba.y, bc.y);
      float xx2 = fminf(ba.z, bc.z);
      float yy2 = fminf(ba.w, bc.w);
      float inter = fmaxf(xx2 - xx1 + 1.0f, 0.0f) * fmaxf(yy2 - yy1 + 1.0f, 0.0f);
      float un = aA + areaC - inter;
      float q = inter * __builtin_amdgcn_rcpf(un);
      bool hi = q > NMS_T + MARG;
      bool lo = q < NMS_T - MARG;
      bool sup = hi;
      if (__ballot(ok && !hi && !lo)) {
        if (!hi && !lo) sup = (inter / un) > NMS_T;
      }
      ok = ok && !sup;
    }
    u64 wm = __ballot(ok);                   // full-exec ballot
    if (lane == 0) okm[wave] = wm;
    __syncthreads();
    if (wave == 0) {
      u64 m = okm[0];
      #pragma unroll
      for (int w = 1; w < 16; ++w) m &= okm[w];
      bool ok0 = (m >> lane) & 1ull;
      int nAcc = nA;
      u64 bal = __ballot(ok0);
      while (bal != 0ull && nAcc < POST) {
        int fl = __ffsll(bal) - 1;
        float ax1 = __int_as_float(__builtin_amdgcn_readlane(__float_as_int(bc.x), fl));
        float ay1 = __int_as_float(__builtin_amdgcn_readlane(__float_as_int(bc.y), fl));
        float ax2 = __int_as_float(__builtin_amdgcn_readlane(__float_as_int(bc.z), fl));
        float ay2 = __int_as_float(__builtin_amdgcn_readlane(__float_as_int(bc.w), fl));
        float aA = (ax2 - ax1 + 1.0f) * (ay2 - ay1 + 1.0f);
        if (lane == 0) { accB[nAcc] = make_float4(ax1, ay1, ax2, ay2); accA[nAcc] = aA; }
        ++nAcc;
        if (ok0) {
          if (lane == fl) ok0 = false;
          else if (lane > fl) {
            float xx1 = fmaxf(ax1, bc.x);
            float yy1 = fmaxf(ay1, bc.y);
            float xx2 = fminf(ax2, bc.z);
            float yy2 = fminf(ay2, bc.w);
            float inter = fmaxf(xx2 - xx1 + 1.0f, 0.0f) * fmaxf(yy2 - yy1 + 1.0f, 0.0f);
            float iou = inter / (aA + areaC - inter);
            if (iou > NMS_T) ok0 = false;
          }
        }
        bal = __ballot(ok0);
      }
      if (lane == 0) scal[4] = nAcc;
    }
    __syncthreads();
  }

  // ---- output: [b][POST][5] = (b, x1, y1, x2, y2); rows >= nAcc zeroed ----
  const int nAcc = scal[4];
  float* ob = out + (size_t)b * POST * 5;
  for (int i = tid; i < POST * 5; i += 1024) {
    int row = i / 5, col = i - row * 5;
    float v = 0.f;
    if (col == 0) v = (float)b;
    else if (row < nAcc) {
      float4 bb = accB[row];
      v = (col == 1) ? bb.x : (col == 2) ? bb.y : (col == 3) ? bb.z : bb.w;
    }
    ob[i] = v;
  }
}

extern "C" void kernel_launch(void* const* d_in, const int* in_sizes, int n_in,
                              void* d_out, int out_size, void* d_ws, size_t ws_size,
                              hipStream_t stream) {
  const float* cls     = (const float*)d_in[0];
  const float* pred    = (const float*)d_in[1];
  const float* iminfo  = (const float*)d_in[2];
  const float* anchors = (const float*)d_in[3];
  float* out = (float*)d_out;

  u32* histg  = (u32*)d_ws;                              // 32*4096*4 = 512 KB
  u32* scoreg = (u32*)((char*)d_ws + 524288);            // 32*90000*4 = 11.52 MB

  k_zero<<<(NB*4096 + 1023)/1024, 1024, 0, stream>>>(histg);
  k_decode<<<NB*NSLICE, 1024, 0, stream>>>(cls, pred, iminfo, anchors, scoreg, histg);
  k_fused<<<NB, 1024, 0, stream>>>(scoreg, histg, pred, iminfo, anchors, out);
}

// Round 13
// 206.310 us; speedup vs baseline: 3.4386x; 1.1576x over previous
//
#include <hip/hip_runtime.h>

#define NB 32
#define NA 9
#define FH 100
#define FW 100
#define HWSZ (FH*FW)          // 10000
#define NANCH (HWSZ*NA)       // 90000
#define PRE 6000
#define POST 300
#define SORTN 8192
#define NEGV -1000000000.0f
#define NMS_T 0.7f
#define MARG 1e-4f
#define NCHUNK ((PRE + 63) / 64)   // 94
#define WB() __builtin_amdgcn_wave_barrier()
#define NSLICE 11                 // slices per batch: 11*8192 >= 90000
#define DSLICE 8192

typedef unsigned long long u64;
typedef unsigned int u32;

__device__ __forceinline__ u32 f2sort(float f) {
  u32 u = __float_as_uint(f);
  return (u & 0x80000000u) ? ~u : (u | 0x80000000u);
}

__device__ __forceinline__ float4 decode_box(const float* __restrict__ pred,
                                             const float* __restrict__ anchors,
                                             int b, int i, float imw, float imh) {
  int hw = i / NA; int a = i - hw * NA;
  int h = hw / FW; int w = hw - h * FW;
  float sx = (float)(w * 16);
  float sy = (float)(h * 16);
  float ax1 = anchors[a*4+0] + sx, ay1 = anchors[a*4+1] + sy;
  float ax2 = anchors[a*4+2] + sx, ay2 = anchors[a*4+3] + sy;
  float wa = ax2 - ax1 + 1.0f, ha = ay2 - ay1 + 1.0f;
  float cxa = ax1 + 0.5f*(wa - 1.0f), cya = ay1 + 0.5f*(ha - 1.0f);
  size_t base = (((size_t)b*36 + a*4)*FH + h)*FW + w;
  float dx = pred[base];
  float dy = pred[base + HWSZ];
  float dw = pred[base + 2*HWSZ];
  float dh = pred[base + 3*HWSZ];
  float cx = dx*wa + cxa, cy = dy*ha + cya;
  float pw = expf(dw)*wa, ph = expf(dh)*ha;
  float x1 = fminf(fmaxf(cx - 0.5f*(pw - 1.0f), 0.0f), imw - 1.0f);
  float y1 = fminf(fmaxf(cy - 0.5f*(ph - 1.0f), 0.0f), imh - 1.0f);
  float x2 = fminf(fmaxf(cx + 0.5f*(pw - 1.0f), 0.0f), imw - 1.0f);
  float y2 = fminf(fmaxf(cy + 0.5f*(ph - 1.0f), 0.0f), imh - 1.0f);
  return make_float4(x1, y1, x2, y2);
}

// K0: zero histg+binCnt (contiguous 262144 u32) and candg (1048576 u32)
__global__ void k_zero(u32* __restrict__ histcnt, u32* __restrict__ cand32) {
  int i = blockIdx.x * 1024 + threadIdx.x;
  if (i < 262144) histcnt[i] = 0;
  cand32[i] = 0;          // grid sized exactly 1048576
}

// K1: per-anchor score + min-size filter -> sortable u32; fused LINEAR hist
__global__ __launch_bounds__(1024) void k_decode(
    const float* __restrict__ cls,
    const float* __restrict__ pred,
    const float* __restrict__ iminfo,
    const float* __restrict__ anchors,
    u32* __restrict__ scoreg,
    u32* __restrict__ histg) {
  __shared__ u32 hl[4096];
  const int blk = blockIdx.x;
  const int b = blk / NSLICE, s = blk - b * NSLICE;
  const int tid = threadIdx.x;
  for (int j = tid; j < 4096; j += 1024) hl[j] = 0;
  __syncthreads();
  const float imh = iminfo[b*3+0], imw = iminfo[b*3+1], sc = iminfo[b*3+2];
  const float msz = 16.0f * sc;
  #pragma unroll
  for (int r = 0; r < 8; ++r) {
    int i = s * DSLICE + r * 1024 + tid;
    if (i < NANCH) {
      int hw = i / NA; int a = i - hw * NA;
      int h = hw / FW; int w = hw - h * FW;
      float score = cls[(((size_t)b*18 + 9 + a)*FH + h)*FW + w];
      float4 bx = decode_box(pred, anchors, b, i, imw, imh);
      bool keep = ((bx.z - bx.x + 1.0f) >= msz) && ((bx.w - bx.y + 1.0f) >= msz);
      float sf = keep ? score : NEGV;
      float t = sf * 4096.0f;
      int bin = (t <= 0.0f) ? 0 : ((t >= 4095.0f) ? 4095 : (int)t);
      atomicAdd(&hl[bin], 1u);
      scoreg[(size_t)b * NANCH + i] = f2sort(sf);
    }
  }
  __syncthreads();
  for (int j = tid; j < 4096; j += 1024) {
    u32 v = hl[j];
    if (v) atomicAdd(&histg[b * 4096 + j], v);
  }
}

// wave suffix cut search over 4096-bin histogram (LDS).
__device__ __forceinline__ void w0_cut(u32* hist, u32 target, int lane,
                                       int* cutBin) {
  u32 cs = 0;
  int cb = lane * 64;
  for (int i = 0; i < 64; ++i) cs += hist[cb + ((i + lane) & 63)];
  u32 suf = cs;
  #pragma unroll
  for (int d = 1; d < 64; d <<= 1) {
    u32 o = __shfl_down(suf, (unsigned)d, 64);
    suf += (lane < 64 - d) ? o : 0u;
  }
  u64 m1 = __ballot(suf >= target);
  int L = 63 - __clzll(m1);
  u32 nAb = (L < 63) ? (u32)__builtin_amdgcn_readlane((int)suf, L + 1) : 0u;
  u32 fs = hist[L * 64 + lane];
  #pragma unroll
  for (int d = 1; d < 64; d <<= 1) {
    u32 o = __shfl_down(fs, (unsigned)d, 64);
    fs += (lane < 64 - d) ? o : 0u;
  }
  fs += nAb;
  u64 m2 = __ballot(fs >= target);
  int fb = 63 - __clzll(m2);
  *cutBin = L * 64 + fb;
}

// K2: per-batch (1 wave): cut bin + thrT + descending-suffix binStart
__global__ __launch_bounds__(64) void k_cut(const u32* __restrict__ histg,
                                            u32* __restrict__ thrTg,
                                            u32* __restrict__ binStartG) {
  __shared__ u32 hl[4096];
  const int b = blockIdx.x, lane = threadIdx.x;
  const u32* h = histg + b * 4096;
  for (int i = lane; i < 4096; i += 64) hl[i] = h[i];
  __syncthreads();
  int L;
  w0_cut(hl, PRE, lane, &L);
  u32 running = 0;
  for (int hi = 4095; hi >= L; hi -= 64) {
    int bin = hi - lane;
    u32 c = (bin >= L && bin >= 0) ? hl[bin] : 0u;
    u32 p = c;
    #pragma unroll
    for (int d = 1; d < 64; d <<= 1) {
      u32 o = __shfl_up(p, (unsigned)d, 64);
      if (lane >= d) p += o;
    }
    if (bin >= L && bin >= 0) binStartG[b * 4096 + bin] = running + p - c;
    running += (u32)__builtin_amdgcn_readlane((int)p, 63);
  }
  if (lane == 0) thrTg[b] = f2sort((float)L * (1.0f / 4096.0f));
}

// K3: parallel scatter into bin segments (arbitrary order within bin)
__global__ __launch_bounds__(1024) void k_scatter(
    const u32* __restrict__ scoreg,
    const u32* __restrict__ thrTg,
    const u32* __restrict__ binStartG,
    u32* __restrict__ binCntG,
    u64* __restrict__ candg) {
  const int blk = blockIdx.x;
  const int b = blk / NSLICE, s = blk - b * NSLICE;
  const int tid = threadIdx.x;
  const u32 thrT = thrTg[b];
  const u32* sb = scoreg + (size_t)b * NANCH;
  #pragma unroll
  for (int r = 0; r < 8; ++r) {
    int i = s * DSLICE + r * 1024 + tid;
    if (i < NANCH) {
      u32 sv = sb[i];
      if (sv >= thrT) {
        float f = __uint_as_float(sv ^ 0x80000000u);
        float t = f * 4096.0f;
        int bin = (t >= 4095.0f) ? 4095 : (int)t;
        u32 pos = binStartG[b * 4096 + bin] + atomicAdd(&binCntG[b * 4096 + bin], 1u);
        if (pos < SORTN) candg[(size_t)b * SORTN + pos] = ((u64)sv << 32) | (u32)(~(u32)i);
      }
    }
  }
}

// K4: one wave per (batch,bin): sort tiny segment descending by full u64 key
__global__ __launch_bounds__(1024) void k_binsort(
    const u32* __restrict__ binStartG,
    const u32* __restrict__ binCntG,
    u64* __restrict__ candg) {
  __shared__ u64 sc[16][512];
  const int wave = threadIdx.x >> 6, lane = threadIdx.x & 63;
  const int task = blockIdx.x * 16 + wave;       // 131072 = 32 * 4096
  const int b = task >> 12, bin = task & 4095;
  u32 cnt = binCntG[b * 4096 + bin];
  if (cnt < 2) return;
  u32 base = binStartG[b * 4096 + bin];
  if (base >= SORTN) return;
  u32 m = cnt;
  if (base + m > SORTN) m = SORTN - base;
  u64* seg = candg + (size_t)b * SORTN + base;
  if (m <= 64) {
    u64 v = (lane < (int)m) ? seg[lane] : 0ull;
    #pragma unroll
    for (int k = 2; k <= 64; k <<= 1) {
      for (int j = k >> 1; j > 0; j >>= 1) {
        u64 o = __shfl_xor((unsigned long long)v, j, 64);
        bool dirD = ((lane & k) == 0);
        bool lower = ((lane & j) == 0);
        bool takeMax = (dirD == lower);
        bool sw = takeMax ? (o > v) : (o < v);
        if (sw) v = o;
      }
    }
    if (lane < (int)m) seg[lane] = v;
  } else if (m <= 512) {
    int np = 128; while (np < (int)m) np <<= 1;
    for (int i = lane; i < np; i += 64) sc[wave][i] = (i < (int)m) ? seg[i] : 0ull;
    WB();
    for (int k = 2; k <= np; k <<= 1) {
      for (int j = k >> 1; j > 0; j >>= 1) {
        for (int q = lane; q < np/2; q += 64) {
          int i = ((q & ~(j-1)) << 1) | (q & (j-1));
          int x = i | j;
          u64 a0 = sc[wave][i], a1 = sc[wave][x];
          bool up = (i & k) != 0;
          if (up ? (a0 > a1) : (a0 < a1)) { sc[wave][i] = a1; sc[wave][x] = a0; }
        }
        WB();
      }
    }
    for (int i = lane; i < (int)m; i += 64) seg[i] = sc[wave][i];
  }
}

// K5: 32 blocks: Phase A decode-all -> LDS; Phase B 16-wave NMS
// LDS: boxes float4[6016] @0..96256; liveM u64[96] @96256; accB @97024;
// accA @101824; okm @103040; scal @103168; aL @103232. -> 103424
#define SMEM_BYTES 103424
__global__ __launch_bounds__(1024, 1) void k_nms(
    const u64* __restrict__ candg,
    const float* __restrict__ pred,
    const float* __restrict__ iminfo,
    const float* __restrict__ anchors,
    float* __restrict__ out) {
  __shared__ __align__(16) unsigned char smemRaw[SMEM_BYTES];
  float4* boxes = (float4*)smemRaw;
  u64* liveM = (u64*)(smemRaw + 96256);
  float4* accB = (float4*)(smemRaw + 97024);
  float* accA = (float*)(smemRaw + 101824);
  u64* okm = (u64*)(smemRaw + 103040);
  int* scal = (int*)(smemRaw + 103168);
  float* aL = (float*)(smemRaw + 103232);

  const int b = blockIdx.x;
  const int tid = threadIdx.x;
  const int wave = tid >> 6, lane = tid & 63;
  const u32 liveThr = f2sort(-5.0e8f);
  const u64* cb = candg + (size_t)b * SORTN;

  if (tid < 36) aL[tid] = anchors[tid];
  if (tid == 0) scal[4] = 0;
  __syncthreads();

  // ---- Phase A: decode all 6016 candidate boxes into LDS ----
  const float imh = iminfo[b*3+0], imw = iminfo[b*3+1];
  #pragma unroll
  for (int r = 0; r < 6; ++r) {
    int c = wave + 16 * r;                   // wave-uniform chunk; i = 64c+lane
    if (c < NCHUNK) {
      int i = tid + 1024 * r;
      u64 k = cb[i];
      int idx = (int)(~(u32)k);
      bool v = (u32)idx < (u32)NANCH;
      bool live = ((u32)(k >> 32) > liveThr) && v && (i < PRE);
      int id = v ? idx : 0;
      int hw = id / NA; int a = id - hw * NA;
      int h = hw / FW; int w = hw - h * FW;
      float sx = (float)(w * 16), sy = (float)(h * 16);
      float ax1 = aL[a*4+0] + sx, ay1 = aL[a*4+1] + sy;
      float ax2 = aL[a*4+2] + sx, ay2 = aL[a*4+3] + sy;
      float wa = ax2 - ax1 + 1.0f, ha = ay2 - ay1 + 1.0f;
      float cxa = ax1 + 0.5f*(wa - 1.0f), cya = ay1 + 0.5f*(ha - 1.0f);
      size_t base = (((size_t)b*36 + a*4)*FH + h)*FW + w;
      float dx = pred[base], dy = pred[base + HWSZ];
      float dw = pred[base + 2*HWSZ], dh = pred[base + 3*HWSZ];
      float cx = dx*wa + cxa, cy = dy*ha + cya;
      float pw = expf(dw)*wa, ph = expf(dh)*ha;
      float4 bc;
      bc.x = fminf(fmaxf(cx - 0.5f*(pw - 1.0f), 0.0f), imw - 1.0f);
      bc.y = fminf(fmaxf(cy - 0.5f*(ph - 1.0f), 0.0f), imh - 1.0f);
      bc.z = fminf(fmaxf(cx + 0.5f*(pw - 1.0f), 0.0f), imw - 1.0f);
      bc.w = fminf(fmaxf(cy + 0.5f*(ph - 1.0f), 0.0f), imh - 1.0f);
      boxes[i] = bc;
      u64 lm = __ballot(live);
      if (lane == 0) liveM[c] = lm;
    }
  }
  __syncthreads();

  // ---- Phase B: per chunk, 16-wave-parallel accepted-list testing ----
  for (int g = 0; g < NCHUNK; ++g) {
    int nA = scal[4];
    if (nA >= POST) break;                   // uniform
    u64 lm = liveM[g];
    if (lm == 0ull) continue;                // uniform skip
    float4 bc = boxes[g * 64 + lane];
    float areaC = (bc.z - bc.x + 1.0f) * (bc.w - bc.y + 1.0f);
    bool ok = (lm >> lane) & 1ull;
    for (int tt = wave; tt < nA; tt += 16) { // independent iters, pipelined
      float4 ba = accB[tt];
      float aA = accA[tt];
      float xx1 = fmaxf(ba.x, bc.x);
      float yy1 = fmaxf(ba.y, bc.y);
      float xx2 = fminf(ba.z, bc.z);
      float yy2 = fminf(ba.w, bc.w);
      float inter = fmaxf(xx2 - xx1 + 1.0f, 0.0f) * fmaxf(yy2 - yy1 + 1.0f, 0.0f);
      float un = aA + areaC - inter;
      float q = inter * __builtin_amdgcn_rcpf(un);
      bool hi = q > NMS_T + MARG;
      bool lo = q < NMS_T - MARG;
      bool sup = hi;
      if (__ballot(ok && !hi && !lo)) {      // rare exact-div fallback
        if (!hi && !lo) sup = (inter / un) > NMS_T;
      }
      ok = ok && !sup;
    }
    u64 wm = __ballot(ok);                   // full-exec ballot
    if (lane == 0) okm[wave] = wm;
    __syncthreads();
    if (wave == 0) {
      u64 m = okm[0];
      #pragma unroll
      for (int w = 1; w < 16; ++w) m &= okm[w];
      bool ok0 = (m >> lane) & 1ull;
      int nAcc = nA;
      u64 bal = __ballot(ok0);
      while (bal != 0ull && nAcc < POST) {
        int fl = __ffsll(bal) - 1;
        float ax1 = __int_as_float(__builtin_amdgcn_readlane(__float_as_int(bc.x), fl));
        float ay1 = __int_as_float(__builtin_amdgcn_readlane(__float_as_int(bc.y), fl));
        float ax2 = __int_as_float(__builtin_amdgcn_readlane(__float_as_int(bc.z), fl));
        float ay2 = __int_as_float(__builtin_amdgcn_readlane(__float_as_int(bc.w), fl));
        float aA = (ax2 - ax1 + 1.0f) * (ay2 - ay1 + 1.0f);
        if (lane == 0) { accB[nAcc] = make_float4(ax1, ay1, ax2, ay2); accA[nAcc] = aA; }
        ++nAcc;
        if (ok0) {
          if (lane == fl) ok0 = false;
          else if (lane > fl) {
            float xx1 = fmaxf(ax1, bc.x);
            float yy1 = fmaxf(ay1, bc.y);
            float xx2 = fminf(ax2, bc.z);
            float yy2 = fminf(ay2, bc.w);
            float inter = fmaxf(xx2 - xx1 + 1.0f, 0.0f) * fmaxf(yy2 - yy1 + 1.0f, 0.0f);
            float iou = inter / (aA + areaC - inter);
            if (iou > NMS_T) ok0 = false;
          }
        }
        bal = __ballot(ok0);
      }
      if (lane == 0) scal[4] = nAcc;
    }
    __syncthreads();
  }

  // ---- output: [b][POST][5] = (b, x1, y1, x2, y2); rows >= nAcc zeroed ----
  const int nAcc = scal[4];
  float* ob = out + (size_t)b * POST * 5;
  for (int i = tid; i < POST * 5; i += 1024) {
    int row = i / 5, col = i - row * 5;
    float v = 0.f;
    if (col == 0) v = (float)b;
    else if (row < nAcc) {
      float4 bb = accB[row];
      v = (col == 1) ? bb.x : (col == 2) ? bb.y : (col == 3) ? bb.z : bb.w;
    }
    ob[i] = v;
  }
}

extern "C" void kernel_launch(void* const* d_in, const int* in_sizes, int n_in,
                              void* d_out, int out_size, void* d_ws, size_t ws_size,
                              hipStream_t stream) {
  const float* cls     = (const float*)d_in[0];
  const float* pred    = (const float*)d_in[1];
  const float* iminfo  = (const float*)d_in[2];
  const float* anchors = (const float*)d_in[3];
  float* out = (float*)d_out;

  char* ws = (char*)d_ws;
  u32* histg     = (u32*)(ws + 0);            // 512 KB
  u32* binCntG   = (u32*)(ws + 524288);       // 512 KB (contiguous after histg)
  u32* binStartG = (u32*)(ws + 1048576);      // 512 KB
  u32* thrTg     = (u32*)(ws + 1572864);      // 128 B
  u64* candg     = (u64*)(ws + 1572992);      // 2 MB (32*8192*8)
  u32* scoreg    = (u32*)(ws + 3670144);      // 11.52 MB

  k_zero<<<1024, 1024, 0, stream>>>(histg, (u32*)candg);
  k_decode<<<NB*NSLICE, 1024, 0, stream>>>(cls, pred, iminfo, anchors, scoreg, histg);
  k_cut<<<NB, 64, 0, stream>>>(histg, thrTg, binStartG);
  k_scatter<<<NB*NSLICE, 1024, 0, stream>>>(scoreg, thrTg, binStartG, binCntG, candg);
  k_binsort<<<8192, 1024, 0, stream>>>(binStartG, binCntG, candg);
  k_nms<<<NB, 1024, 0, stream>>>(candg, pred, iminfo, anchors, out);
}